// Round 7
// baseline (360.531 us; speedup 1.0000x reference)
//
#include <hip/hip_runtime.h>
#include <hip/hip_bf16.h>

typedef unsigned short u16;
typedef __attribute__((ext_vector_type(8))) __bf16 bf16x8;
typedef __attribute__((ext_vector_type(4))) float f32x4;
typedef __attribute__((ext_vector_type(4))) unsigned short u16x4;

#define SCALE_QK 0.08838834764831845f

__device__ __forceinline__ u16 f2bf(float x) {
  union { float f; unsigned u; } v; v.f = x;
  unsigned r = v.u + 0x7fffu + ((v.u >> 16) & 1u);
  return (u16)(r >> 16);
}

__device__ __forceinline__ void gload_lds16(const u16* g, u16* l) {
  __builtin_amdgcn_global_load_lds(
      (const __attribute__((address_space(1))) unsigned*)g,
      (__attribute__((address_space(3))) unsigned*)l, 16, 0, 0);
}

#define CFENCE() asm volatile("" ::: "memory")
#define WAITV(N) asm volatile("s_waitcnt vmcnt(" #N ")" ::: "memory")

// ===========================================================================
// g128m: m201-faithful phase body. 256x128 tile, BK=32, THREE-buffer LDS
// rotation (72 KiB -> 2 blocks/CU), one phase per K-tile:
//   {ds_read(tile t, buf t%3) ; STG(tile t+2 -> buf (t+2)%3) ; WAITV(3) ;
//    BAR ; lgkmcnt(0)+sched_barrier ; setprio1 16xMFMA setprio0 ; BAR}
// Ledger: tile t's data confirmed at phase t-1 (WAITV(3) leaves only tile
// t+1's 3 loads outstanding, then BAR) -> reads at phase t safe. STG(t+2)
// writes buf(t-1) whose last reads drained at t-1's lgkm(0) before BAR2.
// vmcnt never 0 until peeled tail (t=NT-2: WAITV(0); t=NT-1: none).
// 8 waves 4Mx2N, wave tile 64x64, acc[4][4]. Swizzle: 8-elem slot
// g' = g ^ ((row>>1)&3) on global source + ds_read addr; LDS dest linear.
// Buf b at b*12288 elems: A [256][32] @0 (16KB), B [128][32] @8192 (8KB).
// Requires K%32==0, K>=96. Optional 2nd K-segment accumulates into acc.
// ===========================================================================
template<bool OUT_BF16, bool HAS_BIAS, bool TWO_SEG>
__global__ __launch_bounds__(512, 2)
void g128m(const u16* __restrict__ A1, int lda1, long sA1,
           const u16* __restrict__ B1, int ldb1, long sB1, int K1,
           const u16* __restrict__ A2, int lda2, long sA2,
           const u16* __restrict__ B2, int ldb2, long sB2, int K2,
           void* __restrict__ Cv, int ldc, long sC,
           float scale, const float* __restrict__ bias, int nbx)
{
  extern __shared__ u16 lds[];
  const int bz = blockIdx.z;
  const int nwg = gridDim.x, orig = blockIdx.x;
  const int q8 = nwg >> 3, r8 = nwg & 7;
  const int xcd = orig & 7, lp = orig >> 3;
  const int wg = (xcd < r8 ? xcd * (q8 + 1) : r8 * (q8 + 1) + (xcd - r8) * q8) + lp;
  const int bx = wg % nbx, by = wg / nbx;
  const long m0 = (long)by * 256, n0 = (long)bx * 128;

  const int tid = threadIdx.x, wid = tid >> 6, lane = tid & 63;
  const int wm = wid >> 1, wn = wid & 1;
  const int rl = lane & 15, g = lane >> 4;
  const int sw = ((g ^ ((rl >> 1) & 3)) << 3);

  int aoff[4], boff[4];
#pragma unroll
  for (int i = 0; i < 4; ++i) aoff[i] = (wm * 64 + i * 16 + rl) * 32 + sw;
#pragma unroll
  for (int j = 0; j < 4; ++j) boff[j] = 8192 + (wn * 64 + j * 16 + rl) * 32 + sw;

  const int srow = tid >> 2;                               // 0..127
  const int scolX = (((tid & 3) ^ ((srow >> 1) & 3)) << 3);

  f32x4 acc[4][4];
#pragma unroll
  for (int i = 0; i < 4; ++i)
#pragma unroll
    for (int j = 0; j < 4; ++j) acc[i][j] = (f32x4){0.f, 0.f, 0.f, 0.f};

  bf16x8 av[4], bv[4];

#define STG(H_, BS_) {                                                   \
    const u16* sa_ = Ab + (long)srow * lda + (H_) * 32 + scolX;          \
    u16* da_ = lds + (BS_) * 12288 + tid * 8;                            \
    gload_lds16(sa_, da_);                                               \
    gload_lds16(sa_ + (long)128 * lda, da_ + 4096);                      \
    gload_lds16(Bb + (long)srow * ldb + (H_) * 32 + scolX,               \
                lds + (BS_) * 12288 + 8192 + tid * 8); }
#define RD(BT_) {                                                        \
    const u16* bp_ = lds + (BT_) * 12288;                                \
    _Pragma("unroll") for (int i_ = 0; i_ < 4; ++i_)                     \
      av[i_] = *(const bf16x8*)(bp_ + aoff[i_]);                         \
    _Pragma("unroll") for (int j_ = 0; j_ < 4; ++j_)                     \
      bv[j_] = *(const bf16x8*)(bp_ + boff[j_]); }
#define MMTAIL()                                                         \
    CFENCE(); __builtin_amdgcn_s_barrier();                              \
    asm volatile("s_waitcnt lgkmcnt(0)" ::: "memory");                   \
    __builtin_amdgcn_sched_barrier(0);                                   \
    __builtin_amdgcn_s_setprio(1);                                       \
    _Pragma("unroll") for (int i_ = 0; i_ < 4; ++i_)                     \
      _Pragma("unroll") for (int j_ = 0; j_ < 4; ++j_)                   \
        acc[i_][j_] = __builtin_amdgcn_mfma_f32_16x16x32_bf16(           \
            av[i_], bv[j_], acc[i_][j_], 0, 0, 0);                       \
    __builtin_amdgcn_s_setprio(0);                                       \
    CFENCE(); __builtin_amdgcn_s_barrier(); CFENCE();

  const int NSEG = TWO_SEG ? 2 : 1;
#pragma unroll 1
  for (int seg = 0; seg < NSEG; ++seg) {
    const int lda = (seg == 0) ? lda1 : lda2;
    const int ldb = (seg == 0) ? ldb1 : ldb2;
    const int K   = (seg == 0) ? K1 : K2;
    const u16* Ab = ((seg == 0) ? A1 + (long)bz * sA1 : A2 + (long)bz * sA2) + m0 * (long)lda;
    const u16* Bb = ((seg == 0) ? B1 + (long)bz * sB1 : B2 + (long)bz * sB2) + n0 * (long)ldb;
    const int NT = K >> 5;   // K-tiles of 32; NT >= 3

    // prologue: stage tiles 0,1; confirm tile 0 (tile 1's 3 loads in flight)
    STG(0, 0); STG(1, 1);
    WAITV(3);
    CFENCE(); __builtin_amdgcn_s_barrier(); CFENCE();

    int bt = 0;
#pragma unroll 1
    for (int t = 0; t < NT - 2; ++t) {
      const int bs = (bt + 2 >= 3) ? bt - 1 : bt + 2;
      RD(bt);
      STG(t + 2, bs);
      WAITV(3);          // confirm tile t+1 (only tile t+2's 3 loads newer)
      MMTAIL();
      bt = (bt + 1 == 3) ? 0 : bt + 1;
    }
    // t = NT-2: no stage; confirm tile NT-1
    RD(bt);
    WAITV(0);
    MMTAIL();
    bt = (bt + 1 == 3) ? 0 : bt + 1;
    // t = NT-1: drain done
    RD(bt);
    MMTAIL();
  }
#undef STG
#undef RD
#undef MMTAIL

  const int r0 = (lane >> 4) << 2;
  const int cL = lane & 15;
#pragma unroll
  for (int i = 0; i < 4; ++i) {
#pragma unroll
    for (int j = 0; j < 4; ++j) {
      const long row = m0 + wm * 64 + i * 16 + r0;
      const long col = n0 + wn * 64 + j * 16 + cL;
      float bvs = 0.f;
      if (HAS_BIAS) bvs = bias[col];
      if (OUT_BF16) {
        u16* Cp = (u16*)Cv + (long)bz * sC;
#pragma unroll
        for (int r = 0; r < 4; ++r)
          Cp[(row + r) * ldc + col] = f2bf(acc[i][j][r] * scale + bvs);
      } else {
        float* Cp = (float*)Cv + (long)bz * sC;
#pragma unroll
        for (int r = 0; r < 4; ++r)
          Cp[(row + r) * ldc + col] = acc[i][j][r] * scale + bvs;
      }
    }
  }
}

// Split-K (x8) variant for skinny GEMM4: atomicAdd f32 epilogue.
__global__ __launch_bounds__(256)
void gemm_bt_splitk(const u16* __restrict__ A, int lda, long sA,
                    const u16* __restrict__ B, int ldb, long sB,
                    float* __restrict__ C, int ldc, long sC,
                    int Kslice, float scale)
{
  __shared__ u16 As[128 * 64];
  __shared__ u16 Bs[128 * 64];
  const int ks = blockIdx.z & 7;
  const int bz = blockIdx.z >> 3;
  const u16* Ap  = A + (long)bz * sA + ks * Kslice;
  const u16* Bp  = B + (long)bz * sB + ks * Kslice;
  const int tid  = threadIdx.x;
  const int wid  = tid >> 6;
  const int lane = tid & 63;
  const long m0  = (long)blockIdx.y * 128;
  const long n0  = (long)blockIdx.x * 128;
  const int lrow = lane >> 3;
  const int lk   = (lane & 7) << 3;
  const int wr   = wid >> 1, wc = wid & 1;

  f32x4 acc[4][4];
#pragma unroll
  for (int i = 0; i < 4; ++i)
#pragma unroll
    for (int j = 0; j < 4; ++j) acc[i][j] = (f32x4){0.f, 0.f, 0.f, 0.f};

  for (int k0 = 0; k0 < Kslice; k0 += 64) {
#pragma unroll
    for (int c4 = 0; c4 < 4; ++c4) {
      const int chunk = (wid << 2) + c4;
      gload_lds16(Ap + (m0 + (chunk << 3) + lrow) * lda + k0 + lk, &As[chunk << 9]);
      gload_lds16(Bp + (n0 + (chunk << 3) + lrow) * ldb + k0 + lk, &Bs[chunk << 9]);
    }
    __syncthreads();
#pragma unroll
    for (int kk = 0; kk < 2; ++kk) {
      bf16x8 af[4], bfr[4];
      const int kof   = (kk << 5) + ((lane >> 4) << 3);
      const int rbase = lane & 15;
#pragma unroll
      for (int i = 0; i < 4; ++i)
        af[i] = *(const bf16x8*)&As[(((wr << 6) + (i << 4) + rbase) << 6) + kof];
#pragma unroll
      for (int j = 0; j < 4; ++j)
        bfr[j] = *(const bf16x8*)&Bs[(((wc << 6) + (j << 4) + rbase) << 6) + kof];
#pragma unroll
      for (int i = 0; i < 4; ++i)
#pragma unroll
        for (int j = 0; j < 4; ++j)
          acc[i][j] = __builtin_amdgcn_mfma_f32_16x16x32_bf16(af[i], bfr[j], acc[i][j], 0, 0, 0);
    }
    __syncthreads();
  }

  const int r0 = (lane >> 4) << 2;
  const int cL = lane & 15;
  float* Cp = C + (long)bz * sC;
#pragma unroll
  for (int i = 0; i < 4; ++i) {
#pragma unroll
    for (int j = 0; j < 4; ++j) {
      const long row = m0 + (wr << 6) + (i << 4) + r0;
      const long col = n0 + (wc << 6) + (j << 4) + cL;
#pragma unroll
      for (int r = 0; r < 4; ++r)
        atomicAdd(&Cp[(row + r) * ldc + col], acc[i][j][r] * scale);
    }
  }
}

// Row softmax over 2048 f32 -> bf16. One block (256 thr) per row.
__global__ __launch_bounds__(256)
void softmax_rows2048(const float* __restrict__ src, u16* __restrict__ dst) {
  const long row = blockIdx.x;
  const float4* s = (const float4*)(src + row * 2048);
  const int tid = threadIdx.x;
  float4 a = s[tid * 2], b = s[tid * 2 + 1];
  float m = fmaxf(fmaxf(fmaxf(a.x, a.y), fmaxf(a.z, a.w)),
                  fmaxf(fmaxf(b.x, b.y), fmaxf(b.z, b.w)));
#pragma unroll
  for (int o = 32; o > 0; o >>= 1) m = fmaxf(m, __shfl_xor(m, o));
  __shared__ float redm[4];
  __shared__ float reds[4];
  if ((tid & 63) == 0) redm[tid >> 6] = m;
  __syncthreads();
  m = fmaxf(fmaxf(redm[0], redm[1]), fmaxf(redm[2], redm[3]));
  float e[8];
  e[0] = __expf(a.x - m); e[1] = __expf(a.y - m); e[2] = __expf(a.z - m); e[3] = __expf(a.w - m);
  e[4] = __expf(b.x - m); e[5] = __expf(b.y - m); e[6] = __expf(b.z - m); e[7] = __expf(b.w - m);
  float sum = e[0] + e[1] + e[2] + e[3] + e[4] + e[5] + e[6] + e[7];
#pragma unroll
  for (int o = 32; o > 0; o >>= 1) sum += __shfl_xor(sum, o);
  if ((tid & 63) == 0) reds[tid >> 6] = sum;
  __syncthreads();
  sum = reds[0] + reds[1] + reds[2] + reds[3];
  const float inv = 1.f / sum;
  u16x4 o1 = { f2bf(e[0] * inv), f2bf(e[1] * inv), f2bf(e[2] * inv), f2bf(e[3] * inv) };
  u16x4 o2 = { f2bf(e[4] * inv), f2bf(e[5] * inv), f2bf(e[6] * inv), f2bf(e[7] * inv) };
  u16x4* d = (u16x4*)(dst + row * 2048);
  d[tid * 2]     = o1;
  d[tid * 2 + 1] = o2;
}

__global__ void transpose_f32_to_bf16(const float* __restrict__ src, u16* __restrict__ dst,
                                      int R, int C) {
  __shared__ float t[32][33];
  const int c0 = blockIdx.x * 32, r0 = blockIdx.y * 32;
  const int tx = threadIdx.x, ty = threadIdx.y;
#pragma unroll
  for (int i = 0; i < 4; ++i)
    t[ty + i * 8][tx] = src[(long)(r0 + ty + i * 8) * C + c0 + tx];
  __syncthreads();
#pragma unroll
  for (int i = 0; i < 4; ++i)
    dst[(long)(c0 + ty + i * 8) * R + r0 + tx] = f2bf(t[tx][ty + i * 8]);
}

__global__ void transpose_bf16_batched(const u16* __restrict__ src, int ss, long sbat,
                                       u16* __restrict__ dst, int ds, long dbat) {
  __shared__ u16 t[32][33];
  const u16* s = src + (long)blockIdx.z * sbat;
  u16* d = dst + (long)blockIdx.z * dbat;
  const int c0 = blockIdx.x * 32, r0 = blockIdx.y * 32;
  const int tx = threadIdx.x, ty = threadIdx.y;
#pragma unroll
  for (int i = 0; i < 4; ++i)
    t[ty + i * 8][tx] = s[(long)(r0 + ty + i * 8) * ss + c0 + tx];
  __syncthreads();
#pragma unroll
  for (int i = 0; i < 4; ++i)
    d[(long)(c0 + ty + i * 8) * ds + r0 + tx] = t[tx][ty + i * 8];
}

__global__ __launch_bounds__(256)
void convert_f32_to_bf16(const float* __restrict__ src, u16* __restrict__ dst, long n4) {
  long i = (long)blockIdx.x * 256 + threadIdx.x;
  if (i < n4) {
    float4 v = ((const float4*)src)[i];
    *(u16x4*)(dst + i * 4) = (u16x4){ f2bf(v.x), f2bf(v.y), f2bf(v.z), f2bf(v.w) };
  }
}

// camT = tanh(ctx * gate) * lw  (lw folded so GEMM2' uses plain SCALE)
__global__ __launch_bounds__(256)
void cam_tanh_kernel(const float* __restrict__ ctx, const float* __restrict__ gate,
                     const float* __restrict__ lw, u16* __restrict__ out, int n) {
  int i = blockIdx.x * 256 + threadIdx.x;
  if (i < n) {
    int d = i & 127;
    out[i] = f2bf(tanhf(ctx[i] * gate[d]) * lw[0]);
  }
}

__global__ __launch_bounds__(256)
void zero_f32(float* __restrict__ p, int n) {
  int i = blockIdx.x * 256 + threadIdx.x;
  if (i < n) p[i] = 0.f;
}

__global__ void calc_lw_kernel(const float* w0, const float* w1, float* lw) {
  *lw = 1.f / (1.f + __expf(-(w0[0] + 0.5f * w1[0])));
}

extern "C" void kernel_launch(void* const* d_in, const int* in_sizes, int n_in,
                              void* d_out, int out_size, void* d_ws, size_t ws_size,
                              hipStream_t stream) {
  const float* hs       = (const float*)d_in[0];
  const float* c_attn_w = (const float*)d_in[1];
  const float* c_attn_b = (const float*)d_in[2];
  const float* c_proj_w = (const float*)d_in[3];
  const float* c_proj_b = (const float*)d_in[4];
  const float* cam_gate = (const float*)d_in[5];
  const float* cam_w0   = (const float*)d_in[6];
  const float* cam_w1   = (const float*)d_in[7];
  float* out = (float*)d_out;

  char* w = (char*)d_ws;
  float* lw      = (float*)(w + 0);
  u16*   hs_b    = (u16*)(w + 256);                  // 16 MB (reused as baseA)
  u16*   waT_b   = (u16*)(w + 256 + 16777216UL);     // 24 MB
  u16*   wpT_b   = (u16*)(w + 256 + 41943040UL);     // 8 MB
  u16*   qkv_b   = (u16*)(w + 256 + 50331648UL);     // 48 MB
  u16*   vT_b    = (u16*)(w + 256 + 100663296UL);    // 16 MB
  float* scoresF = (float*)(w + 256 + 117440512UL);  // 32 MB (reused as ctxE bf16)
  float* camS    = (float*)(w + 256 + 150994944UL);  // 32 MB (reused as P bf16)
  float* ctxF    = (float*)(w + 256 + 184549376UL);  // 2 MB
  u16*   camT_b  = (u16*)(w + 256 + 186646528UL);    // 1 MB
  u16* baseA_b = hs_b;
  u16* P_b     = (u16*)camS;
  u16* ctxE_b  = (u16*)scoresF;

  dim3 b256(256);
  const int LDSB = 73728;   // 3 bufs x 24 KiB

  hipFuncSetAttribute((const void*)g128m<true, true, false>,
                      hipFuncAttributeMaxDynamicSharedMemorySize, LDSB);
  hipFuncSetAttribute((const void*)g128m<false, false, false>,
                      hipFuncAttributeMaxDynamicSharedMemorySize, LDSB);
  hipFuncSetAttribute((const void*)g128m<false, false, true>,
                      hipFuncAttributeMaxDynamicSharedMemorySize, LDSB);
  hipFuncSetAttribute((const void*)g128m<true, false, false>,
                      hipFuncAttributeMaxDynamicSharedMemorySize, LDSB);
  hipFuncSetAttribute((const void*)g128m<false, true, false>,
                      hipFuncAttributeMaxDynamicSharedMemorySize, LDSB);

  calc_lw_kernel<<<dim3(1), dim3(1), 0, stream>>>(cam_w0, cam_w1, lw);
  convert_f32_to_bf16<<<dim3(8192), b256, 0, stream>>>(hs, hs_b, 2097152L);
  transpose_f32_to_bf16<<<dim3(192, 64), dim3(32, 8), 0, stream>>>(c_attn_w, waT_b, 2048, 6144);
  transpose_f32_to_bf16<<<dim3(64, 64), dim3(32, 8), 0, stream>>>(c_proj_w, wpT_b, 2048, 2048);

  // GEMM1: qkv (4096x6144 bf16) = hs @ W_attn + b — 768 blocks, 2 blocks/CU
  g128m<true, true, false><<<dim3(768, 1, 1), dim3(512), LDSB, stream>>>(
      hs_b, 2048, 0L, waT_b, 2048, 0L, 2048,
      nullptr, 0, 0L, nullptr, 0, 0L, 0,
      qkv_b, 6144, 0L, 1.f, c_attn_b, 48);

  // V^T per batch (2048x2048 each)
  transpose_bf16_batched<<<dim3(64, 64, 2), dim3(32, 8), 0, stream>>>(
      qkv_b + 4096, 6144, 2048L * 6144, vT_b, 2048, 2048L * 2048);

  // GEMM3: camS = Q_cam @ K_cam^T * SCALE (K=128, f32)
  g128m<false, false, false><<<dim3(128, 1, 2), dim3(512), LDSB, stream>>>(
      qkv_b, 6144, 2048L * 6144, qkv_b + 2048, 6144, 2048L * 6144, 128,
      nullptr, 0, 0L, nullptr, 0, 0L, 0,
      camS, 2048, 2048L * 2048, SCALE_QK, nullptr, 16);

  // base_A = softmax(camS) -> bf16
  softmax_rows2048<<<dim3(4096), b256, 0, stream>>>(camS, baseA_b);

  // GEMM4: cam_ctx (2048x128 f32 per batch) = base_A @ V_cam — split-K x8
  zero_f32<<<dim3(2048), b256, 0, stream>>>(ctxF, 524288);
  gemm_bt_splitk<<<dim3(1, 16, 16), b256, 0, stream>>>(
      baseA_b, 2048, 2048L * 2048, vT_b, 2048, 2048L * 2048,
      ctxF, 128, 2048L * 128, 256, 1.f);

  // camT = tanh(cam_ctx * gate) * lw -> bf16
  cam_tanh_kernel<<<dim3(2048), b256, 0, stream>>>(ctxF, cam_gate, lw, camT_b, 524288);

  // GEMM2' (fused GEMM5): scores = SCALE*( Q@K^T + camT@K_cam^T ), f32
  g128m<false, false, true><<<dim3(128, 1, 2), dim3(512), LDSB, stream>>>(
      qkv_b, 6144, 2048L * 6144, qkv_b + 2048, 6144, 2048L * 6144, 2048,
      camT_b, 128, 2048L * 128, qkv_b + 2048, 6144, 2048L * 6144, 128,
      scoresF, 2048, 2048L * 2048, SCALE_QK, nullptr, 16);

  // P = softmax(scores) -> bf16
  softmax_rows2048<<<dim3(4096), b256, 0, stream>>>(scoresF, P_b);

  // GEMM6: context (bf16) = P @ V
  g128m<true, false, false><<<dim3(128, 1, 2), dim3(512), LDSB, stream>>>(
      P_b, 2048, 2048L * 2048, vT_b, 2048, 2048L * 2048, 2048,
      nullptr, 0, 0L, nullptr, 0, 0L, 0,
      ctxE_b, 2048, 2048L * 2048, 1.f, nullptr, 16);

  // GEMM7: out (f32) = context @ W_proj + b  (batches stacked: M=4096)
  g128m<false, true, false><<<dim3(256, 1, 1), dim3(512), LDSB, stream>>>(
      ctxE_b, 2048, 0L, wpT_b, 2048, 0L, 2048,
      nullptr, 0, 0L, nullptr, 0, 0L, 0,
      out, 2048, 0L, 1.f, c_proj_b, 16);
}

// Round 8
// 353.013 us; speedup vs baseline: 1.0213x; 1.0213x over previous
//
#include <hip/hip_runtime.h>
#include <hip/hip_bf16.h>

typedef unsigned short u16;
typedef __attribute__((ext_vector_type(8))) __bf16 bf16x8;
typedef __attribute__((ext_vector_type(4))) float f32x4;
typedef __attribute__((ext_vector_type(4))) unsigned short u16x4;

#define SCALE_QK 0.08838834764831845f

__device__ __forceinline__ u16 f2bf(float x) {
  union { float f; unsigned u; } v; v.f = x;
  unsigned r = v.u + 0x7fffu + ((v.u >> 16) & 1u);
  return (u16)(r >> 16);
}

__device__ __forceinline__ void gload_lds16(const u16* g, u16* l) {
  __builtin_amdgcn_global_load_lds(
      (const __attribute__((address_space(1))) unsigned*)g,
      (__attribute__((address_space(3))) unsigned*)l, 16, 0, 0);
}

#define CFENCE() asm volatile("" ::: "memory")
#define WAITV(N) asm volatile("s_waitcnt vmcnt(" #N ")" ::: "memory")

// ===========================================================================
// g128d: round-6 g128p with pipeline depth 6 (was 4). 256x128 tile, kk-half
// (K=32) units, 6-slot LDS rotation (144 KiB, 1 block/CU), ONE barrier per
// phase, register-double-buffered fragments:
//   body(k): WAITV(12) ; BAR ; lgkm(0)+sched_barrier ; prio1 16xMFMA prio0 ;
//            RD(k+1)->other regs ; STG(k+6) .
// Ledger: WAITV(12) leaves slots k+2..k+5 (4x3 loads) outstanding -> slot k+1
// confirmed before RD(k+1). Stage->consume lag = 5 bodies (~1000cy >= HBM).
// STG(k+6) overwrites slot k%6 whose reads (RD(k) in body k-1) are
// lgkm(0)-drained by body k for every wave (same ledger as round 6).
// vmcnt never 0 until peeled tail (12,9,6,3,0,-). 8 waves 4Mx2N, wave tile
// 64x64. LDS elems: A slot s at s*8192 ([256][32]); B slot s at 49152+s*4096
// ([128][32]). Swizzle: 8-elem slot g' = g ^ ((row>>1)&3) on global source +
// ds_read addr; gload_lds dest linear (rule #21).
// Generic path requires K%64==0, K>=512; NT==4 path handles K=128 (seg 2).
// ===========================================================================
template<bool OUT_BF16, bool HAS_BIAS, bool TWO_SEG>
__global__ __launch_bounds__(512, 2)
void g128d(const u16* __restrict__ A1, int lda1, long sA1,
           const u16* __restrict__ B1, int ldb1, long sB1, int K1,
           const u16* __restrict__ A2, int lda2, long sA2,
           const u16* __restrict__ B2, int ldb2, long sB2, int K2,
           void* __restrict__ Cv, int ldc, long sC,
           float scale, const float* __restrict__ bias, int nbx)
{
  extern __shared__ u16 lds[];
  const int bz = blockIdx.z;
  const int nwg = gridDim.x, orig = blockIdx.x;
  const int q8 = nwg >> 3, r8 = nwg & 7;
  const int xcd = orig & 7, lp = orig >> 3;
  const int wg = (xcd < r8 ? xcd * (q8 + 1) : r8 * (q8 + 1) + (xcd - r8) * q8) + lp;
  const int bx = wg % nbx, by = wg / nbx;
  const long m0 = (long)by * 256, n0 = (long)bx * 128;

  const int tid = threadIdx.x, wid = tid >> 6, lane = tid & 63;
  const int wm = wid >> 1, wn = wid & 1;
  const int rl = lane & 15, g = lane >> 4;
  const int sw = ((g ^ ((rl >> 1) & 3)) << 3);

  int aoff[4], boff[4];
#pragma unroll
  for (int i = 0; i < 4; ++i) aoff[i] = (wm * 64 + i * 16 + rl) * 32 + sw;
#pragma unroll
  for (int j = 0; j < 4; ++j) boff[j] = (wn * 64 + j * 16 + rl) * 32 + sw;

  const int srow = tid >> 2;                               // 0..127
  const int scolX = (((tid & 3) ^ ((srow >> 1) & 3)) << 3);

  f32x4 acc[4][4];
#pragma unroll
  for (int i = 0; i < 4; ++i)
#pragma unroll
    for (int j = 0; j < 4; ++j) acc[i][j] = (f32x4){0.f, 0.f, 0.f, 0.f};

  bf16x8 avA[4], bvA[4], avB[4], bvB[4];

#define STG6(H_, OA_) {                                                  \
    const u16* sa_ = Ab + (long)srow * lda + (H_) * 32 + scolX;          \
    u16* da_ = lds + (OA_) + tid * 8;                                    \
    gload_lds16(sa_, da_);                                               \
    gload_lds16(sa_ + (long)128 * lda, da_ + 4096);                      \
    gload_lds16(Bb + (long)srow * ldb + (H_) * 32 + scolX,               \
                lds + 49152 + ((OA_) >> 1) + tid * 8); }
#define RD6(OA_, AV, BV) {                                               \
    const u16* ap_ = lds + (OA_);                                        \
    const u16* bp_ = lds + 49152 + ((OA_) >> 1);                         \
    _Pragma("unroll") for (int i_ = 0; i_ < 4; ++i_)                     \
      AV[i_] = *(const bf16x8*)(ap_ + aoff[i_]);                         \
    _Pragma("unroll") for (int j_ = 0; j_ < 4; ++j_)                     \
      BV[j_] = *(const bf16x8*)(bp_ + boff[j_]); }
#define MMCL(CAV, CBV)                                                   \
    CFENCE(); __builtin_amdgcn_s_barrier();                              \
    asm volatile("s_waitcnt lgkmcnt(0)" ::: "memory");                   \
    __builtin_amdgcn_sched_barrier(0);                                   \
    __builtin_amdgcn_s_setprio(1);                                       \
    _Pragma("unroll") for (int i_ = 0; i_ < 4; ++i_)                     \
      _Pragma("unroll") for (int j_ = 0; j_ < 4; ++j_)                   \
        acc[i_][j_] = __builtin_amdgcn_mfma_f32_16x16x32_bf16(           \
            CAV[i_], CBV[j_], acc[i_][j_], 0, 0, 0);                     \
    __builtin_amdgcn_s_setprio(0);

  const int NSEG = TWO_SEG ? 2 : 1;
#pragma unroll 1
  for (int seg = 0; seg < NSEG; ++seg) {
    const int lda = (seg == 0) ? lda1 : lda2;
    const int ldb = (seg == 0) ? ldb1 : ldb2;
    const int K   = (seg == 0) ? K1 : K2;
    const u16* Ab = ((seg == 0) ? A1 + (long)bz * sA1 : A2 + (long)bz * sA2) + m0 * (long)lda;
    const u16* Bb = ((seg == 0) ? B1 + (long)bz * sB1 : B2 + (long)bz * sB2) + n0 * (long)ldb;
    const int NT = K >> 5;   // kk-halves

    if (NT == 4) {
      // ---- small-K path (K=128): 4 tiles, no steady loop
      STG6(0, 0); STG6(1, 8192); STG6(2, 16384); STG6(3, 24576);
      WAITV(9);
      CFENCE(); __builtin_amdgcn_s_barrier(); CFENCE();
      RD6(0, avA, bvA);
      CFENCE();
      WAITV(6); MMCL(avA, bvA); RD6(8192,  avB, bvB); CFENCE();
      WAITV(3); MMCL(avB, bvB); RD6(16384, avA, bvA); CFENCE();
      WAITV(0); MMCL(avA, bvA); RD6(24576, avB, bvB); CFENCE();
      MMCL(avB, bvB); CFENCE();
      __builtin_amdgcn_s_barrier();
      CFENCE();
    } else {
      // ---- generic path: NT even, NT >= 8
      STG6(0, 0); STG6(1, 8192); STG6(2, 16384); STG6(3, 24576); STG6(4, 32768);
      WAITV(12);
      CFENCE(); __builtin_amdgcn_s_barrier(); CFENCE();
      RD6(0, avA, bvA);
      STG6(5, 40960);
      CFENCE();

      int rdo = 8192;   // slot of tile 1 (next read)
      int sto = 0;      // slot of tile 6 (next stage)
      int hst = 6;      // next tile index to stage

#pragma unroll 1
      for (int k = 0; k < NT - 6; k += 2) {
        WAITV(12);
        MMCL(avA, bvA);
        RD6(rdo, avB, bvB); rdo += 8192; if (rdo == 49152) rdo = 0;
        STG6(hst, sto); ++hst; sto += 8192; if (sto == 49152) sto = 0;
        CFENCE();
        WAITV(12);
        MMCL(avB, bvB);
        RD6(rdo, avA, bvA); rdo += 8192; if (rdo == 49152) rdo = 0;
        STG6(hst, sto); ++hst; sto += 8192; if (sto == 49152) sto = 0;
        CFENCE();
      }
      // peeled tail: bodies NT-6 .. NT-1 (no staging)
      WAITV(12); MMCL(avA, bvA);
      RD6(rdo, avB, bvB); rdo += 8192; if (rdo == 49152) rdo = 0; CFENCE();
      WAITV(9);  MMCL(avB, bvB);
      RD6(rdo, avA, bvA); rdo += 8192; if (rdo == 49152) rdo = 0; CFENCE();
      WAITV(6);  MMCL(avA, bvA);
      RD6(rdo, avB, bvB); rdo += 8192; if (rdo == 49152) rdo = 0; CFENCE();
      WAITV(3);  MMCL(avB, bvB);
      RD6(rdo, avA, bvA); rdo += 8192; if (rdo == 49152) rdo = 0; CFENCE();
      WAITV(0);  MMCL(avA, bvA);
      RD6(rdo, avB, bvB); CFENCE();
      MMCL(avB, bvB); CFENCE();
      __builtin_amdgcn_s_barrier();
      CFENCE();
    }
  }
#undef STG6
#undef RD6
#undef MMCL

  const int r0 = (lane >> 4) << 2;
  const int cL = lane & 15;
#pragma unroll
  for (int i = 0; i < 4; ++i) {
#pragma unroll
    for (int j = 0; j < 4; ++j) {
      const long row = m0 + wm * 64 + i * 16 + r0;
      const long col = n0 + wn * 64 + j * 16 + cL;
      float bvs = 0.f;
      if (HAS_BIAS) bvs = bias[col];
      if (OUT_BF16) {
        u16* Cp = (u16*)Cv + (long)bz * sC;
#pragma unroll
        for (int r = 0; r < 4; ++r)
          Cp[(row + r) * ldc + col] = f2bf(acc[i][j][r] * scale + bvs);
      } else {
        float* Cp = (float*)Cv + (long)bz * sC;
#pragma unroll
        for (int r = 0; r < 4; ++r)
          Cp[(row + r) * ldc + col] = acc[i][j][r] * scale + bvs;
      }
    }
  }
}

// ---------------------------------------------------------------------------
// Legacy 128x128 kernel for GEMM3 (K=128).
// ---------------------------------------------------------------------------
template<bool OUT_BF16, bool HAS_BIAS>
__global__ __launch_bounds__(256)
void gemm_bt(const u16* __restrict__ A, int lda, long sA,
             const u16* __restrict__ B, int ldb, long sB,
             void* __restrict__ Cv, int ldc, long sC,
             int K, float scale, const float* __restrict__ bias)
{
  __shared__ u16 As[128 * 64];
  __shared__ u16 Bs[128 * 64];
  const int bz   = blockIdx.z;
  const u16* Ap  = A + (long)bz * sA;
  const u16* Bp  = B + (long)bz * sB;
  const int tid  = threadIdx.x;
  const int wid  = tid >> 6;
  const int lane = tid & 63;
  const long m0  = (long)blockIdx.y * 128;
  const long n0  = (long)blockIdx.x * 128;
  const int lrow = lane >> 3;
  const int lk   = (lane & 7) << 3;
  const int wr   = wid >> 1, wc = wid & 1;

  f32x4 acc[4][4];
#pragma unroll
  for (int i = 0; i < 4; ++i)
#pragma unroll
    for (int j = 0; j < 4; ++j) acc[i][j] = (f32x4){0.f, 0.f, 0.f, 0.f};

  for (int k0 = 0; k0 < K; k0 += 64) {
#pragma unroll
    for (int c4 = 0; c4 < 4; ++c4) {
      const int chunk = (wid << 2) + c4;
      gload_lds16(Ap + (m0 + (chunk << 3) + lrow) * lda + k0 + lk, &As[chunk << 9]);
      gload_lds16(Bp + (n0 + (chunk << 3) + lrow) * ldb + k0 + lk, &Bs[chunk << 9]);
    }
    __syncthreads();
#pragma unroll
    for (int kk = 0; kk < 2; ++kk) {
      bf16x8 af[4], bfr[4];
      const int kof   = (kk << 5) + ((lane >> 4) << 3);
      const int rbase = lane & 15;
#pragma unroll
      for (int i = 0; i < 4; ++i)
        af[i] = *(const bf16x8*)&As[(((wr << 6) + (i << 4) + rbase) << 6) + kof];
#pragma unroll
      for (int j = 0; j < 4; ++j)
        bfr[j] = *(const bf16x8*)&Bs[(((wc << 6) + (j << 4) + rbase) << 6) + kof];
#pragma unroll
      for (int i = 0; i < 4; ++i)
#pragma unroll
        for (int j = 0; j < 4; ++j)
          acc[i][j] = __builtin_amdgcn_mfma_f32_16x16x32_bf16(af[i], bfr[j], acc[i][j], 0, 0, 0);
    }
    __syncthreads();
  }

  const int r0 = (lane >> 4) << 2;
  const int cL = lane & 15;
#pragma unroll
  for (int i = 0; i < 4; ++i) {
#pragma unroll
    for (int j = 0; j < 4; ++j) {
      const long row = m0 + (wr << 6) + (i << 4) + r0;
      const long col = n0 + (wc << 6) + (j << 4) + cL;
      float bv = 0.f;
      if (HAS_BIAS) bv = bias[col];
      if (OUT_BF16) {
        u16* Cp = (u16*)Cv + (long)bz * sC;
#pragma unroll
        for (int r = 0; r < 4; ++r)
          Cp[(row + r) * ldc + col] = f2bf(acc[i][j][r] * scale + bv);
      } else {
        float* Cp = (float*)Cv + (long)bz * sC;
#pragma unroll
        for (int r = 0; r < 4; ++r)
          Cp[(row + r) * ldc + col] = acc[i][j][r] * scale + bv;
      }
    }
  }
}

// Split-K (x8) variant for skinny GEMM4: atomicAdd f32 epilogue.
__global__ __launch_bounds__(256)
void gemm_bt_splitk(const u16* __restrict__ A, int lda, long sA,
                    const u16* __restrict__ B, int ldb, long sB,
                    float* __restrict__ C, int ldc, long sC,
                    int Kslice, float scale)
{
  __shared__ u16 As[128 * 64];
  __shared__ u16 Bs[128 * 64];
  const int ks = blockIdx.z & 7;
  const int bz = blockIdx.z >> 3;
  const u16* Ap  = A + (long)bz * sA + ks * Kslice;
  const u16* Bp  = B + (long)bz * sB + ks * Kslice;
  const int tid  = threadIdx.x;
  const int wid  = tid >> 6;
  const int lane = tid & 63;
  const long m0  = (long)blockIdx.y * 128;
  const long n0  = (long)blockIdx.x * 128;
  const int lrow = lane >> 3;
  const int lk   = (lane & 7) << 3;
  const int wr   = wid >> 1, wc = wid & 1;

  f32x4 acc[4][4];
#pragma unroll
  for (int i = 0; i < 4; ++i)
#pragma unroll
    for (int j = 0; j < 4; ++j) acc[i][j] = (f32x4){0.f, 0.f, 0.f, 0.f};

  for (int k0 = 0; k0 < Kslice; k0 += 64) {
#pragma unroll
    for (int c4 = 0; c4 < 4; ++c4) {
      const int chunk = (wid << 2) + c4;
      gload_lds16(Ap + (m0 + (chunk << 3) + lrow) * lda + k0 + lk, &As[chunk << 9]);
      gload_lds16(Bp + (n0 + (chunk << 3) + lrow) * ldb + k0 + lk, &Bs[chunk << 9]);
    }
    __syncthreads();
#pragma unroll
    for (int kk = 0; kk < 2; ++kk) {
      bf16x8 af[4], bfr[4];
      const int kof   = (kk << 5) + ((lane >> 4) << 3);
      const int rbase = lane & 15;
#pragma unroll
      for (int i = 0; i < 4; ++i)
        af[i] = *(const bf16x8*)&As[(((wr << 6) + (i << 4) + rbase) << 6) + kof];
#pragma unroll
      for (int j = 0; j < 4; ++j)
        bfr[j] = *(const bf16x8*)&Bs[(((wc << 6) + (j << 4) + rbase) << 6) + kof];
#pragma unroll
      for (int i = 0; i < 4; ++i)
#pragma unroll
        for (int j = 0; j < 4; ++j)
          acc[i][j] = __builtin_amdgcn_mfma_f32_16x16x32_bf16(af[i], bfr[j], acc[i][j], 0, 0, 0);
    }
    __syncthreads();
  }

  const int r0 = (lane >> 4) << 2;
  const int cL = lane & 15;
  float* Cp = C + (long)bz * sC;
#pragma unroll
  for (int i = 0; i < 4; ++i) {
#pragma unroll
    for (int j = 0; j < 4; ++j) {
      const long row = m0 + (wr << 6) + (i << 4) + r0;
      const long col = n0 + (wc << 6) + (j << 4) + cL;
#pragma unroll
      for (int r = 0; r < 4; ++r)
        atomicAdd(&Cp[(row + r) * ldc + col], acc[i][j][r] * scale);
    }
  }
}

// Row softmax over 2048 f32 -> bf16. One block (256 thr) per row.
__global__ __launch_bounds__(256)
void softmax_rows2048(const float* __restrict__ src, u16* __restrict__ dst) {
  const long row = blockIdx.x;
  const float4* s = (const float4*)(src + row * 2048);
  const int tid = threadIdx.x;
  float4 a = s[tid * 2], b = s[tid * 2 + 1];
  float m = fmaxf(fmaxf(fmaxf(a.x, a.y), fmaxf(a.z, a.w)),
                  fmaxf(fmaxf(b.x, b.y), fmaxf(b.z, b.w)));
#pragma unroll
  for (int o = 32; o > 0; o >>= 1) m = fmaxf(m, __shfl_xor(m, o));
  __shared__ float redm[4];
  __shared__ float reds[4];
  if ((tid & 63) == 0) redm[tid >> 6] = m;
  __syncthreads();
  m = fmaxf(fmaxf(redm[0], redm[1]), fmaxf(redm[2], redm[3]));
  float e[8];
  e[0] = __expf(a.x - m); e[1] = __expf(a.y - m); e[2] = __expf(a.z - m); e[3] = __expf(a.w - m);
  e[4] = __expf(b.x - m); e[5] = __expf(b.y - m); e[6] = __expf(b.z - m); e[7] = __expf(b.w - m);
  float sum = e[0] + e[1] + e[2] + e[3] + e[4] + e[5] + e[6] + e[7];
#pragma unroll
  for (int o = 32; o > 0; o >>= 1) sum += __shfl_xor(sum, o);
  if ((tid & 63) == 0) reds[tid >> 6] = sum;
  __syncthreads();
  sum = reds[0] + reds[1] + reds[2] + reds[3];
  const float inv = 1.f / sum;
  u16x4 o1 = { f2bf(e[0] * inv), f2bf(e[1] * inv), f2bf(e[2] * inv), f2bf(e[3] * inv) };
  u16x4 o2 = { f2bf(e[4] * inv), f2bf(e[5] * inv), f2bf(e[6] * inv), f2bf(e[7] * inv) };
  u16x4* d = (u16x4*)(dst + row * 2048);
  d[tid * 2]     = o1;
  d[tid * 2 + 1] = o2;
}

__global__ void transpose_f32_to_bf16(const float* __restrict__ src, u16* __restrict__ dst,
                                      int R, int C) {
  __shared__ float t[32][33];
  const int c0 = blockIdx.x * 32, r0 = blockIdx.y * 32;
  const int tx = threadIdx.x, ty = threadIdx.y;
#pragma unroll
  for (int i = 0; i < 4; ++i)
    t[ty + i * 8][tx] = src[(long)(r0 + ty + i * 8) * C + c0 + tx];
  __syncthreads();
#pragma unroll
  for (int i = 0; i < 4; ++i)
    dst[(long)(c0 + ty + i * 8) * R + r0 + tx] = f2bf(t[tx][ty + i * 8]);
}

__global__ void transpose_bf16_batched(const u16* __restrict__ src, int ss, long sbat,
                                       u16* __restrict__ dst, int ds, long dbat) {
  __shared__ u16 t[32][33];
  const u16* s = src + (long)blockIdx.z * sbat;
  u16* d = dst + (long)blockIdx.z * dbat;
  const int c0 = blockIdx.x * 32, r0 = blockIdx.y * 32;
  const int tx = threadIdx.x, ty = threadIdx.y;
#pragma unroll
  for (int i = 0; i < 4; ++i)
    t[ty + i * 8][tx] = s[(long)(r0 + ty + i * 8) * ss + c0 + tx];
  __syncthreads();
#pragma unroll
  for (int i = 0; i < 4; ++i)
    d[(long)(c0 + ty + i * 8) * ds + r0 + tx] = t[tx][ty + i * 8];
}

__global__ __launch_bounds__(256)
void convert_f32_to_bf16(const float* __restrict__ src, u16* __restrict__ dst, long n4) {
  long i = (long)blockIdx.x * 256 + threadIdx.x;
  if (i < n4) {
    float4 v = ((const float4*)src)[i];
    *(u16x4*)(dst + i * 4) = (u16x4){ f2bf(v.x), f2bf(v.y), f2bf(v.z), f2bf(v.w) };
  }
}

// camT = tanh(ctx * gate) * lw  (lw folded so GEMM2' uses plain SCALE)
__global__ __launch_bounds__(256)
void cam_tanh_kernel(const float* __restrict__ ctx, const float* __restrict__ gate,
                     const float* __restrict__ lw, u16* __restrict__ out, int n) {
  int i = blockIdx.x * 256 + threadIdx.x;
  if (i < n) {
    int d = i & 127;
    out[i] = f2bf(tanhf(ctx[i] * gate[d]) * lw[0]);
  }
}

__global__ __launch_bounds__(256)
void zero_f32(float* __restrict__ p, int n) {
  int i = blockIdx.x * 256 + threadIdx.x;
  if (i < n) p[i] = 0.f;
}

__global__ void calc_lw_kernel(const float* w0, const float* w1, float* lw) {
  *lw = 1.f / (1.f + __expf(-(w0[0] + 0.5f * w1[0])));
}

extern "C" void kernel_launch(void* const* d_in, const int* in_sizes, int n_in,
                              void* d_out, int out_size, void* d_ws, size_t ws_size,
                              hipStream_t stream) {
  const float* hs       = (const float*)d_in[0];
  const float* c_attn_w = (const float*)d_in[1];
  const float* c_attn_b = (const float*)d_in[2];
  const float* c_proj_w = (const float*)d_in[3];
  const float* c_proj_b = (const float*)d_in[4];
  const float* cam_gate = (const float*)d_in[5];
  const float* cam_w0   = (const float*)d_in[6];
  const float* cam_w1   = (const float*)d_in[7];
  float* out = (float*)d_out;

  char* w = (char*)d_ws;
  float* lw      = (float*)(w + 0);
  u16*   hs_b    = (u16*)(w + 256);                  // 16 MB (reused as baseA)
  u16*   waT_b   = (u16*)(w + 256 + 16777216UL);     // 24 MB
  u16*   wpT_b   = (u16*)(w + 256 + 41943040UL);     // 8 MB
  u16*   qkv_b   = (u16*)(w + 256 + 50331648UL);     // 48 MB
  u16*   vT_b    = (u16*)(w + 256 + 100663296UL);    // 16 MB
  float* scoresF = (float*)(w + 256 + 117440512UL);  // 32 MB (reused as ctxE bf16)
  float* camS    = (float*)(w + 256 + 150994944UL);  // 32 MB (reused as P bf16)
  float* ctxF    = (float*)(w + 256 + 184549376UL);  // 2 MB
  u16*   camT_b  = (u16*)(w + 256 + 186646528UL);    // 1 MB
  u16* baseA_b = hs_b;
  u16* P_b     = (u16*)camS;
  u16* ctxE_b  = (u16*)scoresF;

  dim3 b256(256);
  const int LDSB = 147456;   // 6 slots x (16K A + 8K B)

  hipFuncSetAttribute((const void*)g128d<true, true, false>,
                      hipFuncAttributeMaxDynamicSharedMemorySize, LDSB);
  hipFuncSetAttribute((const void*)g128d<false, false, true>,
                      hipFuncAttributeMaxDynamicSharedMemorySize, LDSB);
  hipFuncSetAttribute((const void*)g128d<true, false, false>,
                      hipFuncAttributeMaxDynamicSharedMemorySize, LDSB);
  hipFuncSetAttribute((const void*)g128d<false, true, false>,
                      hipFuncAttributeMaxDynamicSharedMemorySize, LDSB);

  calc_lw_kernel<<<dim3(1), dim3(1), 0, stream>>>(cam_w0, cam_w1, lw);
  convert_f32_to_bf16<<<dim3(8192), b256, 0, stream>>>(hs, hs_b, 2097152L);
  transpose_f32_to_bf16<<<dim3(192, 64), dim3(32, 8), 0, stream>>>(c_attn_w, waT_b, 2048, 6144);
  transpose_f32_to_bf16<<<dim3(64, 64), dim3(32, 8), 0, stream>>>(c_proj_w, wpT_b, 2048, 2048);

  // GEMM1: qkv (4096x6144 bf16) = hs @ W_attn + b — 768 blocks
  g128d<true, true, false><<<dim3(768, 1, 1), dim3(512), LDSB, stream>>>(
      hs_b, 2048, 0L, waT_b, 2048, 0L, 2048,
      nullptr, 0, 0L, nullptr, 0, 0L, 0,
      qkv_b, 6144, 0L, 1.f, c_attn_b, 48);

  // V^T per batch (2048x2048 each)
  transpose_bf16_batched<<<dim3(64, 64, 2), dim3(32, 8), 0, stream>>>(
      qkv_b + 4096, 6144, 2048L * 6144, vT_b, 2048, 2048L * 2048);

  // GEMM3: camS = Q_cam @ K_cam^T * SCALE (K=128, f32)
  gemm_bt<false, false><<<dim3(16, 16, 2), b256, 0, stream>>>(
      qkv_b, 6144, 2048L * 6144, qkv_b + 2048, 6144, 2048L * 6144,
      camS, 2048, 2048L * 2048, 128, SCALE_QK, nullptr);

  // base_A = softmax(camS) -> bf16
  softmax_rows2048<<<dim3(4096), b256, 0, stream>>>(camS, baseA_b);

  // GEMM4: cam_ctx (2048x128 f32 per batch) = base_A @ V_cam — split-K x8
  zero_f32<<<dim3(2048), b256, 0, stream>>>(ctxF, 524288);
  gemm_bt_splitk<<<dim3(1, 16, 16), b256, 0, stream>>>(
      baseA_b, 2048, 2048L * 2048, vT_b, 2048, 2048L * 2048,
      ctxF, 128, 2048L * 128, 256, 1.f);

  // camT = tanh(cam_ctx * gate) * lw -> bf16
  cam_tanh_kernel<<<dim3(2048), b256, 0, stream>>>(ctxF, cam_gate, lw, camT_b, 524288);

  // GEMM2' (fused GEMM5): scores = SCALE*( Q@K^T + camT@K_cam^T ), f32
  g128d<false, false, true><<<dim3(128, 1, 2), dim3(512), LDSB, stream>>>(
      qkv_b, 6144, 2048L * 6144, qkv_b + 2048, 6144, 2048L * 6144, 2048,
      camT_b, 128, 2048L * 128, qkv_b + 2048, 6144, 2048L * 6144, 128,
      scoresF, 2048, 2048L * 2048, SCALE_QK, nullptr, 16);

  // P = softmax(scores) -> bf16
  softmax_rows2048<<<dim3(4096), b256, 0, stream>>>(scoresF, P_b);

  // GEMM6: context (bf16) = P @ V
  g128d<true, false, false><<<dim3(128, 1, 2), dim3(512), LDSB, stream>>>(
      P_b, 2048, 2048L * 2048, vT_b, 2048, 2048L * 2048, 2048,
      nullptr, 0, 0L, nullptr, 0, 0L, 0,
      ctxE_b, 2048, 2048L * 2048, 1.f, nullptr, 16);

  // GEMM7: out (f32) = context @ W_proj + b  (batches stacked: M=4096)
  g128d<false, true, false><<<dim3(256, 1, 1), dim3(512), LDSB, stream>>>(
      ctxE_b, 2048, 0L, wpT_b, 2048, 0L, 2048,
      nullptr, 0, 0L, nullptr, 0, 0L, 0,
      out, 2048, 0L, 1.f, c_proj_b, 16);
}

// Round 9
// 344.981 us; speedup vs baseline: 1.0451x; 1.0233x over previous
//
#include <hip/hip_runtime.h>
#include <hip/hip_bf16.h>

typedef unsigned short u16;
typedef __attribute__((ext_vector_type(8))) __bf16 bf16x8;
typedef __attribute__((ext_vector_type(4))) float f32x4;
typedef __attribute__((ext_vector_type(4))) unsigned short u16x4;

#define SCALE_QK 0.08838834764831845f

__device__ __forceinline__ u16 f2bf(float x) {
  union { float f; unsigned u; } v; v.f = x;
  unsigned r = v.u + 0x7fffu + ((v.u >> 16) & 1u);
  return (u16)(r >> 16);
}

__device__ __forceinline__ void gload_lds16(const u16* g, u16* l) {
  __builtin_amdgcn_global_load_lds(
      (const __attribute__((address_space(1))) unsigned*)g,
      (__attribute__((address_space(3))) unsigned*)l, 16, 0, 0);
}

#define CFENCE() asm volatile("" ::: "memory")
#define WAITV(N) asm volatile("s_waitcnt vmcnt(" #N ")" ::: "memory")

// ===========================================================================
// g128d: 256x128 tile, kk-half (K=32) units, 6-slot LDS rotation (144 KiB),
// ONE barrier per phase, register-double-buffered fragments (round-6/8 body):
//   body(k): WAITV(12) ; BAR ; lgkm(0)+sched_barrier ; prio1 16xMFMA prio0 ;
//            RD(k+1)->other regs ; STG(k+6).
// vmcnt never 0 until peeled tail (12,9,6,3,0,-). 8 waves 4Mx2N.
// LDS elems: A slot s at s*8192 ([256][32]); B slot s at 49152+s*4096.
// Swizzle: 8-elem slot g' = g ^ ((row>>1)&3) on global source + ds_read addr;
// gload_lds dest linear (rule #21).
// mapmode 0: row-major wg (by=wg/nbx). mapmode 1 (GEMM1, nwg=768): per-XCD
// 2D rects — XCD x owns col-stripe [x*6,x*6+6) of 16x48 grid; within stripe
// two 8-row rects, row-fastest -> concurrent set = 8 rows x 4 cols
// (A 8MB + B 2MB per XCD) for L2 locality.
// vTout != nullptr (GEMM1): cols >= 4096 are V -> written transposed to
// vTout[batch][col-4096][row&2047] as u16x4 (skips qkv V region).
// Generic path K%64==0, K>=512 ; NT==4 path handles K=128.
// ===========================================================================
template<bool OUT_BF16, bool HAS_BIAS, bool TWO_SEG>
__global__ __launch_bounds__(512, 2)
void g128d(const u16* __restrict__ A1, int lda1, long sA1,
           const u16* __restrict__ B1, int ldb1, long sB1, int K1,
           const u16* __restrict__ A2, int lda2, long sA2,
           const u16* __restrict__ B2, int ldb2, long sB2, int K2,
           void* __restrict__ Cv, int ldc, long sC,
           float scale, const float* __restrict__ bias, int nbx,
           int mapmode, u16* __restrict__ vTout)
{
  extern __shared__ u16 lds[];
  const int bz = blockIdx.z;
  const int nwg = gridDim.x, orig = blockIdx.x;
  const int q8 = nwg >> 3, r8 = nwg & 7;
  const int xcd = orig & 7, lp = orig >> 3;
  const int wg = (xcd < r8 ? xcd * (q8 + 1) : r8 * (q8 + 1) + (xcd - r8) * q8) + lp;
  int bx, by;
  if (mapmode == 1) {
    const int x = wg / 96, c = wg % 96;
    const int rect = c / 48, i6 = c % 48;
    by = rect * 8 + (i6 & 7);
    bx = x * 6 + (i6 >> 3);
  } else {
    by = wg / nbx; bx = wg % nbx;
  }
  const long m0 = (long)by * 256, n0 = (long)bx * 128;

  const int tid = threadIdx.x, wid = tid >> 6, lane = tid & 63;
  const int wm = wid >> 1, wn = wid & 1;
  const int rl = lane & 15, g = lane >> 4;
  const int sw = ((g ^ ((rl >> 1) & 3)) << 3);

  int aoff[4], boff[4];
#pragma unroll
  for (int i = 0; i < 4; ++i) aoff[i] = (wm * 64 + i * 16 + rl) * 32 + sw;
#pragma unroll
  for (int j = 0; j < 4; ++j) boff[j] = (wn * 64 + j * 16 + rl) * 32 + sw;

  const int srow = tid >> 2;                               // 0..127
  const int scolX = (((tid & 3) ^ ((srow >> 1) & 3)) << 3);

  f32x4 acc[4][4];
#pragma unroll
  for (int i = 0; i < 4; ++i)
#pragma unroll
    for (int j = 0; j < 4; ++j) acc[i][j] = (f32x4){0.f, 0.f, 0.f, 0.f};

  bf16x8 avA[4], bvA[4], avB[4], bvB[4];

#define STG6(H_, OA_) {                                                  \
    const u16* sa_ = Ab + (long)srow * lda + (H_) * 32 + scolX;          \
    u16* da_ = lds + (OA_) + tid * 8;                                    \
    gload_lds16(sa_, da_);                                               \
    gload_lds16(sa_ + (long)128 * lda, da_ + 4096);                      \
    gload_lds16(Bb + (long)srow * ldb + (H_) * 32 + scolX,               \
                lds + 49152 + ((OA_) >> 1) + tid * 8); }
#define RD6(OA_, AV, BV) {                                               \
    const u16* ap_ = lds + (OA_);                                        \
    const u16* bp_ = lds + 49152 + ((OA_) >> 1);                         \
    _Pragma("unroll") for (int i_ = 0; i_ < 4; ++i_)                     \
      AV[i_] = *(const bf16x8*)(ap_ + aoff[i_]);                         \
    _Pragma("unroll") for (int j_ = 0; j_ < 4; ++j_)                     \
      BV[j_] = *(const bf16x8*)(bp_ + boff[j_]); }
#define MMCL(CAV, CBV)                                                   \
    CFENCE(); __builtin_amdgcn_s_barrier();                              \
    asm volatile("s_waitcnt lgkmcnt(0)" ::: "memory");                   \
    __builtin_amdgcn_sched_barrier(0);                                   \
    __builtin_amdgcn_s_setprio(1);                                       \
    _Pragma("unroll") for (int i_ = 0; i_ < 4; ++i_)                     \
      _Pragma("unroll") for (int j_ = 0; j_ < 4; ++j_)                   \
        acc[i_][j_] = __builtin_amdgcn_mfma_f32_16x16x32_bf16(           \
            CAV[i_], CBV[j_], acc[i_][j_], 0, 0, 0);                     \
    __builtin_amdgcn_s_setprio(0);

  const int NSEG = TWO_SEG ? 2 : 1;
#pragma unroll 1
  for (int seg = 0; seg < NSEG; ++seg) {
    const int lda = (seg == 0) ? lda1 : lda2;
    const int ldb = (seg == 0) ? ldb1 : ldb2;
    const int K   = (seg == 0) ? K1 : K2;
    const u16* Ab = ((seg == 0) ? A1 + (long)bz * sA1 : A2 + (long)bz * sA2) + m0 * (long)lda;
    const u16* Bb = ((seg == 0) ? B1 + (long)bz * sB1 : B2 + (long)bz * sB2) + n0 * (long)ldb;
    const int NT = K >> 5;   // kk-halves

    if (NT == 4) {
      // ---- small-K path (K=128): 4 tiles, no steady loop
      STG6(0, 0); STG6(1, 8192); STG6(2, 16384); STG6(3, 24576);
      WAITV(9);
      CFENCE(); __builtin_amdgcn_s_barrier(); CFENCE();
      RD6(0, avA, bvA);
      CFENCE();
      WAITV(6); MMCL(avA, bvA); RD6(8192,  avB, bvB); CFENCE();
      WAITV(3); MMCL(avB, bvB); RD6(16384, avA, bvA); CFENCE();
      WAITV(0); MMCL(avA, bvA); RD6(24576, avB, bvB); CFENCE();
      MMCL(avB, bvB); CFENCE();
      __builtin_amdgcn_s_barrier();
      CFENCE();
    } else {
      // ---- generic path: NT even, NT >= 8
      STG6(0, 0); STG6(1, 8192); STG6(2, 16384); STG6(3, 24576); STG6(4, 32768);
      WAITV(12);
      CFENCE(); __builtin_amdgcn_s_barrier(); CFENCE();
      RD6(0, avA, bvA);
      STG6(5, 40960);
      CFENCE();

      int rdo = 8192;   // slot of tile 1 (next read)
      int sto = 0;      // slot of tile 6 (next stage)
      int hst = 6;      // next tile index to stage

#pragma unroll 1
      for (int k = 0; k < NT - 6; k += 2) {
        WAITV(12);
        MMCL(avA, bvA);
        RD6(rdo, avB, bvB); rdo += 8192; if (rdo == 49152) rdo = 0;
        STG6(hst, sto); ++hst; sto += 8192; if (sto == 49152) sto = 0;
        CFENCE();
        WAITV(12);
        MMCL(avB, bvB);
        RD6(rdo, avA, bvA); rdo += 8192; if (rdo == 49152) rdo = 0;
        STG6(hst, sto); ++hst; sto += 8192; if (sto == 49152) sto = 0;
        CFENCE();
      }
      // peeled tail: bodies NT-6 .. NT-1 (no staging)
      WAITV(12); MMCL(avA, bvA);
      RD6(rdo, avB, bvB); rdo += 8192; if (rdo == 49152) rdo = 0; CFENCE();
      WAITV(9);  MMCL(avB, bvB);
      RD6(rdo, avA, bvA); rdo += 8192; if (rdo == 49152) rdo = 0; CFENCE();
      WAITV(6);  MMCL(avA, bvA);
      RD6(rdo, avB, bvB); rdo += 8192; if (rdo == 49152) rdo = 0; CFENCE();
      WAITV(3);  MMCL(avB, bvB);
      RD6(rdo, avA, bvA); rdo += 8192; if (rdo == 49152) rdo = 0; CFENCE();
      WAITV(0);  MMCL(avA, bvA);
      RD6(rdo, avB, bvB); CFENCE();
      MMCL(avB, bvB); CFENCE();
      __builtin_amdgcn_s_barrier();
      CFENCE();
    }
  }
#undef STG6
#undef RD6
#undef MMCL

  const int r0 = (lane >> 4) << 2;
  const int cL = lane & 15;
#pragma unroll
  for (int i = 0; i < 4; ++i) {
#pragma unroll
    for (int j = 0; j < 4; ++j) {
      const long row = m0 + wm * 64 + i * 16 + r0;
      const long col = n0 + wn * 64 + j * 16 + cL;
      float bvs = 0.f;
      if (HAS_BIAS) bvs = bias[col];
      if (OUT_BF16) {
        u16* Cp = (u16*)Cv + (long)bz * sC;
        if (vTout && col >= 4096) {
          u16x4 t;
#pragma unroll
          for (int r = 0; r < 4; ++r) t[r] = f2bf(acc[i][j][r] * scale + bvs);
          *(u16x4*)(vTout + ((long)(row >> 11) * 2048 + (col - 4096)) * 2048 + (row & 2047)) = t;
        } else {
#pragma unroll
          for (int r = 0; r < 4; ++r)
            Cp[(row + r) * ldc + col] = f2bf(acc[i][j][r] * scale + bvs);
        }
      } else {
        float* Cp = (float*)Cv + (long)bz * sC;
#pragma unroll
        for (int r = 0; r < 4; ++r)
          Cp[(row + r) * ldc + col] = acc[i][j][r] * scale + bvs;
      }
    }
  }
}

// Split-K (x8) variant for skinny GEMM4: atomicAdd f32 epilogue.
__global__ __launch_bounds__(256)
void gemm_bt_splitk(const u16* __restrict__ A, int lda, long sA,
                    const u16* __restrict__ B, int ldb, long sB,
                    float* __restrict__ C, int ldc, long sC,
                    int Kslice, float scale)
{
  __shared__ u16 As[128 * 64];
  __shared__ u16 Bs[128 * 64];
  const int ks = blockIdx.z & 7;
  const int bz = blockIdx.z >> 3;
  const u16* Ap  = A + (long)bz * sA + ks * Kslice;
  const u16* Bp  = B + (long)bz * sB + ks * Kslice;
  const int tid  = threadIdx.x;
  const int wid  = tid >> 6;
  const int lane = tid & 63;
  const long m0  = (long)blockIdx.y * 128;
  const long n0  = (long)blockIdx.x * 128;
  const int lrow = lane >> 3;
  const int lk   = (lane & 7) << 3;
  const int wr   = wid >> 1, wc = wid & 1;

  f32x4 acc[4][4];
#pragma unroll
  for (int i = 0; i < 4; ++i)
#pragma unroll
    for (int j = 0; j < 4; ++j) acc[i][j] = (f32x4){0.f, 0.f, 0.f, 0.f};

  for (int k0 = 0; k0 < Kslice; k0 += 64) {
#pragma unroll
    for (int c4 = 0; c4 < 4; ++c4) {
      const int chunk = (wid << 2) + c4;
      gload_lds16(Ap + (m0 + (chunk << 3) + lrow) * lda + k0 + lk, &As[chunk << 9]);
      gload_lds16(Bp + (n0 + (chunk << 3) + lrow) * ldb + k0 + lk, &Bs[chunk << 9]);
    }
    __syncthreads();
#pragma unroll
    for (int kk = 0; kk < 2; ++kk) {
      bf16x8 af[4], bfr[4];
      const int kof   = (kk << 5) + ((lane >> 4) << 3);
      const int rbase = lane & 15;
#pragma unroll
      for (int i = 0; i < 4; ++i)
        af[i] = *(const bf16x8*)&As[(((wr << 6) + (i << 4) + rbase) << 6) + kof];
#pragma unroll
      for (int j = 0; j < 4; ++j)
        bfr[j] = *(const bf16x8*)&Bs[(((wc << 6) + (j << 4) + rbase) << 6) + kof];
#pragma unroll
      for (int i = 0; i < 4; ++i)
#pragma unroll
        for (int j = 0; j < 4; ++j)
          acc[i][j] = __builtin_amdgcn_mfma_f32_16x16x32_bf16(af[i], bfr[j], acc[i][j], 0, 0, 0);
    }
    __syncthreads();
  }

  const int r0 = (lane >> 4) << 2;
  const int cL = lane & 15;
  float* Cp = C + (long)bz * sC;
#pragma unroll
  for (int i = 0; i < 4; ++i) {
#pragma unroll
    for (int j = 0; j < 4; ++j) {
      const long row = m0 + (wr << 6) + (i << 4) + r0;
      const long col = n0 + (wc << 6) + (j << 4) + cL;
#pragma unroll
      for (int r = 0; r < 4; ++r)
        atomicAdd(&Cp[(row + r) * ldc + col], acc[i][j][r] * scale);
    }
  }
}

// Row softmax over 2048 f32 -> bf16. One block (256 thr) per row.
__global__ __launch_bounds__(256)
void softmax_rows2048(const float* __restrict__ src, u16* __restrict__ dst) {
  const long row = blockIdx.x;
  const float4* s = (const float4*)(src + row * 2048);
  const int tid = threadIdx.x;
  float4 a = s[tid * 2], b = s[tid * 2 + 1];
  float m = fmaxf(fmaxf(fmaxf(a.x, a.y), fmaxf(a.z, a.w)),
                  fmaxf(fmaxf(b.x, b.y), fmaxf(b.z, b.w)));
#pragma unroll
  for (int o = 32; o > 0; o >>= 1) m = fmaxf(m, __shfl_xor(m, o));
  __shared__ float redm[4];
  __shared__ float reds[4];
  if ((tid & 63) == 0) redm[tid >> 6] = m;
  __syncthreads();
  m = fmaxf(fmaxf(redm[0], redm[1]), fmaxf(redm[2], redm[3]));
  float e[8];
  e[0] = __expf(a.x - m); e[1] = __expf(a.y - m); e[2] = __expf(a.z - m); e[3] = __expf(a.w - m);
  e[4] = __expf(b.x - m); e[5] = __expf(b.y - m); e[6] = __expf(b.z - m); e[7] = __expf(b.w - m);
  float sum = e[0] + e[1] + e[2] + e[3] + e[4] + e[5] + e[6] + e[7];
#pragma unroll
  for (int o = 32; o > 0; o >>= 1) sum += __shfl_xor(sum, o);
  if ((tid & 63) == 0) reds[tid >> 6] = sum;
  __syncthreads();
  sum = reds[0] + reds[1] + reds[2] + reds[3];
  const float inv = 1.f / sum;
  u16x4 o1 = { f2bf(e[0] * inv), f2bf(e[1] * inv), f2bf(e[2] * inv), f2bf(e[3] * inv) };
  u16x4 o2 = { f2bf(e[4] * inv), f2bf(e[5] * inv), f2bf(e[6] * inv), f2bf(e[7] * inv) };
  u16x4* d = (u16x4*)(dst + row * 2048);
  d[tid * 2]     = o1;
  d[tid * 2 + 1] = o2;
}

__global__ void transpose_f32_to_bf16(const float* __restrict__ src, u16* __restrict__ dst,
                                      int R, int C) {
  __shared__ float t[32][33];
  const int c0 = blockIdx.x * 32, r0 = blockIdx.y * 32;
  const int tx = threadIdx.x, ty = threadIdx.y;
#pragma unroll
  for (int i = 0; i < 4; ++i)
    t[ty + i * 8][tx] = src[(long)(r0 + ty + i * 8) * C + c0 + tx];
  __syncthreads();
#pragma unroll
  for (int i = 0; i < 4; ++i)
    dst[(long)(c0 + ty + i * 8) * R + r0 + tx] = f2bf(t[tx][ty + i * 8]);
}

__global__ __launch_bounds__(256)
void convert_f32_to_bf16(const float* __restrict__ src, u16* __restrict__ dst, long n4) {
  long i = (long)blockIdx.x * 256 + threadIdx.x;
  if (i < n4) {
    float4 v = ((const float4*)src)[i];
    *(u16x4*)(dst + i * 4) = (u16x4){ f2bf(v.x), f2bf(v.y), f2bf(v.z), f2bf(v.w) };
  }
}

// camT = tanh(ctx * gate) * sigmoid(w0 + 0.5*w1)
__global__ __launch_bounds__(256)
void cam_tanh_kernel(const float* __restrict__ ctx, const float* __restrict__ gate,
                     const float* __restrict__ w0, const float* __restrict__ w1,
                     u16* __restrict__ out, int n) {
  int i = blockIdx.x * 256 + threadIdx.x;
  if (i < n) {
    const float lw = 1.f / (1.f + __expf(-(w0[0] + 0.5f * w1[0])));
    int d = i & 127;
    out[i] = f2bf(tanhf(ctx[i] * gate[d]) * lw);
  }
}

__global__ __launch_bounds__(256)
void zero_f32(float* __restrict__ p, int n) {
  int i = blockIdx.x * 256 + threadIdx.x;
  if (i < n) p[i] = 0.f;
}

extern "C" void kernel_launch(void* const* d_in, const int* in_sizes, int n_in,
                              void* d_out, int out_size, void* d_ws, size_t ws_size,
                              hipStream_t stream) {
  const float* hs       = (const float*)d_in[0];
  const float* c_attn_w = (const float*)d_in[1];
  const float* c_attn_b = (const float*)d_in[2];
  const float* c_proj_w = (const float*)d_in[3];
  const float* c_proj_b = (const float*)d_in[4];
  const float* cam_gate = (const float*)d_in[5];
  const float* cam_w0   = (const float*)d_in[6];
  const float* cam_w1   = (const float*)d_in[7];
  float* out = (float*)d_out;

  char* w = (char*)d_ws;
  u16*   hs_b    = (u16*)(w + 256);                  // 16 MB (reused as baseA)
  u16*   waT_b   = (u16*)(w + 256 + 16777216UL);     // 24 MB
  u16*   wpT_b   = (u16*)(w + 256 + 41943040UL);     // 8 MB
  u16*   qkv_b   = (u16*)(w + 256 + 50331648UL);     // 48 MB
  u16*   vT_b    = (u16*)(w + 256 + 100663296UL);    // 16 MB
  float* scoresF = (float*)(w + 256 + 117440512UL);  // 32 MB (reused as ctxE bf16)
  float* camS    = (float*)(w + 256 + 150994944UL);  // 32 MB (reused as P bf16)
  float* ctxF    = (float*)(w + 256 + 184549376UL);  // 2 MB
  u16*   camT_b  = (u16*)(w + 256 + 186646528UL);    // 1 MB
  u16* baseA_b = hs_b;
  u16* P_b     = (u16*)camS;
  u16* ctxE_b  = (u16*)scoresF;

  dim3 b256(256);
  const int LDSB = 147456;   // 6 slots x (16K A + 8K B)

  hipFuncSetAttribute((const void*)g128d<true, true, false>,
                      hipFuncAttributeMaxDynamicSharedMemorySize, LDSB);
  hipFuncSetAttribute((const void*)g128d<false, false, false>,
                      hipFuncAttributeMaxDynamicSharedMemorySize, LDSB);
  hipFuncSetAttribute((const void*)g128d<false, false, true>,
                      hipFuncAttributeMaxDynamicSharedMemorySize, LDSB);
  hipFuncSetAttribute((const void*)g128d<true, false, false>,
                      hipFuncAttributeMaxDynamicSharedMemorySize, LDSB);
  hipFuncSetAttribute((const void*)g128d<false, true, false>,
                      hipFuncAttributeMaxDynamicSharedMemorySize, LDSB);

  convert_f32_to_bf16<<<dim3(8192), b256, 0, stream>>>(hs, hs_b, 2097152L);
  transpose_f32_to_bf16<<<dim3(192, 64), dim3(32, 8), 0, stream>>>(c_attn_w, waT_b, 2048, 6144);
  transpose_f32_to_bf16<<<dim3(64, 64), dim3(32, 8), 0, stream>>>(c_proj_w, wpT_b, 2048, 2048);

  // GEMM1: qkv = hs @ W_attn + b ; V-columns written transposed to vT_b.
  // mapmode 1: per-XCD 8x4 rects for L2 locality.
  g128d<true, true, false><<<dim3(768, 1, 1), dim3(512), LDSB, stream>>>(
      hs_b, 2048, 0L, waT_b, 2048, 0L, 2048,
      nullptr, 0, 0L, nullptr, 0, 0L, 0,
      qkv_b, 6144, 0L, 1.f, c_attn_b, 48, 1, vT_b);

  // GEMM3: camS = Q_cam @ K_cam^T * SCALE (K=128, f32) — NT=4 path, 256 blocks
  g128d<false, false, false><<<dim3(128, 1, 2), dim3(512), LDSB, stream>>>(
      qkv_b, 6144, 2048L * 6144, qkv_b + 2048, 6144, 2048L * 6144, 128,
      nullptr, 0, 0L, nullptr, 0, 0L, 0,
      camS, 2048, 2048L * 2048, SCALE_QK, nullptr, 16, 0, nullptr);

  // base_A = softmax(camS) -> bf16
  softmax_rows2048<<<dim3(4096), b256, 0, stream>>>(camS, baseA_b);

  // GEMM4: cam_ctx = base_A @ V_cam — split-K x8
  zero_f32<<<dim3(2048), b256, 0, stream>>>(ctxF, 524288);
  gemm_bt_splitk<<<dim3(1, 16, 16), b256, 0, stream>>>(
      baseA_b, 2048, 2048L * 2048, vT_b, 2048, 2048L * 2048,
      ctxF, 128, 2048L * 128, 256, 1.f);

  // camT = tanh(cam_ctx * gate) * lw -> bf16 (lw inline)
  cam_tanh_kernel<<<dim3(2048), b256, 0, stream>>>(ctxF, cam_gate, cam_w0, cam_w1,
                                                   camT_b, 524288);

  // GEMM2' (fused GEMM5): scores = SCALE*( Q@K^T + camT@K_cam^T ), f32
  g128d<false, false, true><<<dim3(128, 1, 2), dim3(512), LDSB, stream>>>(
      qkv_b, 6144, 2048L * 6144, qkv_b + 2048, 6144, 2048L * 6144, 2048,
      camT_b, 128, 2048L * 128, qkv_b + 2048, 6144, 2048L * 6144, 128,
      scoresF, 2048, 2048L * 2048, SCALE_QK, nullptr, 16, 0, nullptr);

  // P = softmax(scores) -> bf16
  softmax_rows2048<<<dim3(4096), b256, 0, stream>>>(scoresF, P_b);

  // GEMM6: context (bf16) = P @ V
  g128d<true, false, false><<<dim3(128, 1, 2), dim3(512), LDSB, stream>>>(
      P_b, 2048, 2048L * 2048, vT_b, 2048, 2048L * 2048, 2048,
      nullptr, 0, 0L, nullptr, 0, 0L, 0,
      ctxE_b, 2048, 2048L * 2048, 1.f, nullptr, 16, 0, nullptr);

  // GEMM7: out (f32) = context @ W_proj + b  (batches stacked: M=4096)
  g128d<false, true, false><<<dim3(256, 1, 1), dim3(512), LDSB, stream>>>(
      ctxE_b, 2048, 0L, wpT_b, 2048, 0L, 2048,
      nullptr, 0, 0L, nullptr, 0, 0L, 0,
      out, 2048, 0L, 1.f, c_proj_b, 16, 0, nullptr);
}

// Round 10
// 331.554 us; speedup vs baseline: 1.0874x; 1.0405x over previous
//
#include <hip/hip_runtime.h>
#include <hip/hip_bf16.h>

typedef unsigned short u16;
typedef __attribute__((ext_vector_type(8))) __bf16 bf16x8;
typedef __attribute__((ext_vector_type(4))) float f32x4;
typedef __attribute__((ext_vector_type(4))) unsigned short u16x4;

#define SCALE_QK 0.08838834764831845f

__device__ __forceinline__ u16 f2bf(float x) {
  union { float f; unsigned u; } v; v.f = x;
  unsigned r = v.u + 0x7fffu + ((v.u >> 16) & 1u);
  return (u16)(r >> 16);
}

__device__ __forceinline__ void gload_lds16(const u16* g, u16* l) {
  __builtin_amdgcn_global_load_lds(
      (const __attribute__((address_space(1))) unsigned*)g,
      (__attribute__((address_space(3))) unsigned*)l, 16, 0, 0);
}

#define CFENCE() asm volatile("" ::: "memory")
#define WAITV(N) asm volatile("s_waitcnt vmcnt(" #N ")" ::: "memory")

// ===========================================================================
// g128q — m201-discipline clone at 256x128 geometry.
// K-tile = 64, THREE buffers (144 KiB), 2 phases per tile:
//  p0(t): RD(A 8 + B01 4, buf t%3)  [buf t confirmed at p0(t-1) WAITV+BAR]
//         STG(tile t+2 -> buf (t-1)%3) ; WAITV(6) [confirms t+1, leaves t+2]
//         BAR ; lgkm(0)+schedbar ; prio1 16xMFMA(j=0,1) prio0 ; BAR
//  p1(t): RD(B23 4) ; BAR ; lgkm(0)+schedbar ; prio1 16xMFMA(j=2,3) prio0 ; BAR
// Reads issue BEFORE the barrier (latency hides under barrier skew; m201
// trick); vmcnt never 0 except the single t=NT-2 drain. Stage->consume lag
// = 2 tiles (~3000cy > HBM). WAR: STG(t+2) hits buf of t-1 whose reads
// drained at p1(t-1) lgkm(0)+BAR.
// 8 waves 4Mx2N (wave tile 64x64). Buf b at b*24576 elems: A [256][64] @0,
// B [128][64] @16384. Swizzle (64-col rows): 8-elem unit u' = u ^ (row&7)
// on global source + ds_read addr; gload_lds dest linear (rule #21).
// Requires K%64==0, NT=K/64 >= 2. mapmode/vTout as round 9.
// ===========================================================================
template<bool OUT_BF16, bool HAS_BIAS, bool TWO_SEG>
__global__ __launch_bounds__(512, 2)
void g128q(const u16* __restrict__ A1, int lda1, long sA1,
           const u16* __restrict__ B1, int ldb1, long sB1, int K1,
           const u16* __restrict__ A2, int lda2, long sA2,
           const u16* __restrict__ B2, int ldb2, long sB2, int K2,
           void* __restrict__ Cv, int ldc, long sC,
           float scale, const float* __restrict__ bias, int nbx,
           int mapmode, u16* __restrict__ vTout)
{
  extern __shared__ u16 lds[];
  const int bz = blockIdx.z;
  const int nwg = gridDim.x, orig = blockIdx.x;
  const int q8 = nwg >> 3, r8 = nwg & 7;
  const int xcd = orig & 7, lp = orig >> 3;
  const int wg = (xcd < r8 ? xcd * (q8 + 1) : r8 * (q8 + 1) + (xcd - r8) * q8) + lp;
  int bx, by;
  if (mapmode == 1) {
    const int x = wg / 96, c = wg % 96;
    const int rect = c / 48, i6 = c % 48;
    by = rect * 8 + (i6 & 7);
    bx = x * 6 + (i6 >> 3);
  } else {
    by = wg / nbx; bx = wg % nbx;
  }
  const long m0 = (long)by * 256, n0 = (long)bx * 128;

  const int tid = threadIdx.x, wid = tid >> 6, lane = tid & 63;
  const int wm = wid >> 1, wn = wid & 1;
  const int rl = lane & 15, g = lane >> 4;
  const int xa = rl & 7;
  const int uk0 = ((g ^ xa) << 3);            // unit for k-frag 0 (bytes/2: elems)
  const int uk1 = (((4 + g) ^ xa) << 3);      // unit for k-frag 1

  int aoffb[4], boffb[4];
#pragma unroll
  for (int i = 0; i < 4; ++i) aoffb[i] = (wm * 64 + i * 16 + rl) * 64;
#pragma unroll
  for (int j = 0; j < 4; ++j) boffb[j] = 16384 + (wn * 64 + j * 16 + rl) * 64;

  const int ra = tid >> 3;                                // 0..63
  const int xcol = (((tid & 7) ^ ((tid >> 3) & 7)) << 3); // swizzled src unit

  f32x4 acc[4][4];
#pragma unroll
  for (int i = 0; i < 4; ++i)
#pragma unroll
    for (int j = 0; j < 4; ++j) acc[i][j] = (f32x4){0.f, 0.f, 0.f, 0.f};

  bf16x8 av[2][4], bv[2][2];

#define STG(T_, BO_) { const int k0_ = (T_) << 6;                        \
    gload_lds16(Ab + (long)(ra      ) * lda + k0_ + xcol, lds + (BO_) +         tid * 8); \
    gload_lds16(Ab + (long)(ra +  64) * lda + k0_ + xcol, lds + (BO_) +  4096 + tid * 8); \
    gload_lds16(Ab + (long)(ra + 128) * lda + k0_ + xcol, lds + (BO_) +  8192 + tid * 8); \
    gload_lds16(Ab + (long)(ra + 192) * lda + k0_ + xcol, lds + (BO_) + 12288 + tid * 8); \
    gload_lds16(Bb + (long)(ra      ) * ldb + k0_ + xcol, lds + (BO_) + 16384 + tid * 8); \
    gload_lds16(Bb + (long)(ra +  64) * ldb + k0_ + xcol, lds + (BO_) + 20480 + tid * 8); }
#define RD0(BO_) { const u16* p_ = lds + (BO_);                          \
    _Pragma("unroll") for (int i_ = 0; i_ < 4; ++i_) {                   \
      av[0][i_] = *(const bf16x8*)(p_ + aoffb[i_] + uk0);                \
      av[1][i_] = *(const bf16x8*)(p_ + aoffb[i_] + uk1); }              \
    _Pragma("unroll") for (int j_ = 0; j_ < 2; ++j_) {                   \
      bv[0][j_] = *(const bf16x8*)(p_ + boffb[j_] + uk0);                \
      bv[1][j_] = *(const bf16x8*)(p_ + boffb[j_] + uk1); } }
#define RD1(BO_) { const u16* p_ = lds + (BO_);                          \
    _Pragma("unroll") for (int j_ = 0; j_ < 2; ++j_) {                   \
      bv[0][j_] = *(const bf16x8*)(p_ + boffb[2 + j_] + uk0);            \
      bv[1][j_] = *(const bf16x8*)(p_ + boffb[2 + j_] + uk1); } }
#define MMPH(JB_)                                                        \
    CFENCE(); __builtin_amdgcn_s_barrier();                              \
    asm volatile("s_waitcnt lgkmcnt(0)" ::: "memory");                   \
    __builtin_amdgcn_sched_barrier(0);                                   \
    __builtin_amdgcn_s_setprio(1);                                       \
    _Pragma("unroll") for (int k_ = 0; k_ < 2; ++k_)                     \
      _Pragma("unroll") for (int i_ = 0; i_ < 4; ++i_)                   \
        _Pragma("unroll") for (int j_ = 0; j_ < 2; ++j_)                 \
          acc[i_][(JB_) + j_] = __builtin_amdgcn_mfma_f32_16x16x32_bf16( \
              av[k_][i_], bv[k_][j_], acc[i_][(JB_) + j_], 0, 0, 0);     \
    __builtin_amdgcn_s_setprio(0);                                       \
    CFENCE(); __builtin_amdgcn_s_barrier(); CFENCE();

  const int NSEG = TWO_SEG ? 2 : 1;
#pragma unroll 1
  for (int seg = 0; seg < NSEG; ++seg) {
    const int lda = (seg == 0) ? lda1 : lda2;
    const int ldb = (seg == 0) ? ldb1 : ldb2;
    const int K   = (seg == 0) ? K1 : K2;
    const u16* Ab = ((seg == 0) ? A1 + (long)bz * sA1 : A2 + (long)bz * sA2) + m0 * (long)lda;
    const u16* Bb = ((seg == 0) ? B1 + (long)bz * sB1 : B2 + (long)bz * sB2) + n0 * (long)ldb;
    const int NT = K >> 6;   // >= 2

    // prologue: stage tiles 0,1 ; confirm tile 0 (leaves tile 1 in flight)
    STG(0, 0); STG(1, 24576);
    WAITV(6);
    CFENCE(); __builtin_amdgcn_s_barrier(); CFENCE();

    int bo = 0;   // buffer offset of tile t (cycles 0,24576,49152)
#pragma unroll 1
    for (int t = 0; t < NT; ++t) {
      // ---- p0
      RD0(bo);
      if (t + 2 < NT) {
        int bos = bo - 24576; if (bos < 0) bos = 49152;   // (t+2)%3 == (t-1)%3
        STG(t + 2, bos);
        WAITV(6);              // confirm tile t+1 (leaves t+2's 6 loads)
      } else if (t + 1 < NT) {
        WAITV(0);              // single drain: confirm tile NT-1
      }
      MMPH(0)
      // ---- p1
      RD1(bo);
      MMPH(2)
      bo += 24576; if (bo == 73728) bo = 0;
    }
  }
#undef STG
#undef RD0
#undef RD1
#undef MMPH

  const int r0 = (lane >> 4) << 2;
  const int cL = lane & 15;
#pragma unroll
  for (int i = 0; i < 4; ++i) {
#pragma unroll
    for (int j = 0; j < 4; ++j) {
      const long row = m0 + wm * 64 + i * 16 + r0;
      const long col = n0 + wn * 64 + j * 16 + cL;
      float bvs = 0.f;
      if (HAS_BIAS) bvs = bias[col];
      if (OUT_BF16) {
        u16* Cp = (u16*)Cv + (long)bz * sC;
        if (vTout && col >= 4096) {
          u16x4 tq;
#pragma unroll
          for (int r = 0; r < 4; ++r) tq[r] = f2bf(acc[i][j][r] * scale + bvs);
          *(u16x4*)(vTout + ((long)(row >> 11) * 2048 + (col - 4096)) * 2048 + (row & 2047)) = tq;
        } else {
#pragma unroll
          for (int r = 0; r < 4; ++r)
            Cp[(row + r) * ldc + col] = f2bf(acc[i][j][r] * scale + bvs);
        }
      } else {
        float* Cp = (float*)Cv + (long)bz * sC;
#pragma unroll
        for (int r = 0; r < 4; ++r)
          Cp[(row + r) * ldc + col] = acc[i][j][r] * scale + bvs;
      }
    }
  }
}

// Split-K (x8) variant for skinny GEMM4: atomicAdd f32 epilogue.
__global__ __launch_bounds__(256)
void gemm_bt_splitk(const u16* __restrict__ A, int lda, long sA,
                    const u16* __restrict__ B, int ldb, long sB,
                    float* __restrict__ C, int ldc, long sC,
                    int Kslice, float scale)
{
  __shared__ u16 As[128 * 64];
  __shared__ u16 Bs[128 * 64];
  const int ks = blockIdx.z & 7;
  const int bz = blockIdx.z >> 3;
  const u16* Ap  = A + (long)bz * sA + ks * Kslice;
  const u16* Bp  = B + (long)bz * sB + ks * Kslice;
  const int tid  = threadIdx.x;
  const int wid  = tid >> 6;
  const int lane = tid & 63;
  const long m0  = (long)blockIdx.y * 128;
  const long n0  = (long)blockIdx.x * 128;
  const int lrow = lane >> 3;
  const int lk   = (lane & 7) << 3;
  const int wr   = wid >> 1, wc = wid & 1;

  f32x4 acc[4][4];
#pragma unroll
  for (int i = 0; i < 4; ++i)
#pragma unroll
    for (int j = 0; j < 4; ++j) acc[i][j] = (f32x4){0.f, 0.f, 0.f, 0.f};

  for (int k0 = 0; k0 < Kslice; k0 += 64) {
#pragma unroll
    for (int c4 = 0; c4 < 4; ++c4) {
      const int chunk = (wid << 2) + c4;
      gload_lds16(Ap + (m0 + (chunk << 3) + lrow) * lda + k0 + lk, &As[chunk << 9]);
      gload_lds16(Bp + (n0 + (chunk << 3) + lrow) * ldb + k0 + lk, &Bs[chunk << 9]);
    }
    __syncthreads();
#pragma unroll
    for (int kk = 0; kk < 2; ++kk) {
      bf16x8 af[4], bfr[4];
      const int kof   = (kk << 5) + ((lane >> 4) << 3);
      const int rbase = lane & 15;
#pragma unroll
      for (int i = 0; i < 4; ++i)
        af[i] = *(const bf16x8*)&As[(((wr << 6) + (i << 4) + rbase) << 6) + kof];
#pragma unroll
      for (int j = 0; j < 4; ++j)
        bfr[j] = *(const bf16x8*)&Bs[(((wc << 6) + (j << 4) + rbase) << 6) + kof];
#pragma unroll
      for (int i = 0; i < 4; ++i)
#pragma unroll
        for (int j = 0; j < 4; ++j)
          acc[i][j] = __builtin_amdgcn_mfma_f32_16x16x32_bf16(af[i], bfr[j], acc[i][j], 0, 0, 0);
    }
    __syncthreads();
  }

  const int r0 = (lane >> 4) << 2;
  const int cL = lane & 15;
  float* Cp = C + (long)bz * sC;
#pragma unroll
  for (int i = 0; i < 4; ++i) {
#pragma unroll
    for (int j = 0; j < 4; ++j) {
      const long row = m0 + (wr << 6) + (i << 4) + r0;
      const long col = n0 + (wc << 6) + (j << 4) + cL;
#pragma unroll
      for (int r = 0; r < 4; ++r)
        atomicAdd(&Cp[(row + r) * ldc + col], acc[i][j][r] * scale);
    }
  }
}

// Row softmax over 2048 f32 -> bf16. One block (256 thr) per row.
__global__ __launch_bounds__(256)
void softmax_rows2048(const float* __restrict__ src, u16* __restrict__ dst) {
  const long row = blockIdx.x;
  const float4* s = (const float4*)(src + row * 2048);
  const int tid = threadIdx.x;
  float4 a = s[tid * 2], b = s[tid * 2 + 1];
  float m = fmaxf(fmaxf(fmaxf(a.x, a.y), fmaxf(a.z, a.w)),
                  fmaxf(fmaxf(b.x, b.y), fmaxf(b.z, b.w)));
#pragma unroll
  for (int o = 32; o > 0; o >>= 1) m = fmaxf(m, __shfl_xor(m, o));
  __shared__ float redm[4];
  __shared__ float reds[4];
  if ((tid & 63) == 0) redm[tid >> 6] = m;
  __syncthreads();
  m = fmaxf(fmaxf(redm[0], redm[1]), fmaxf(redm[2], redm[3]));
  float e[8];
  e[0] = __expf(a.x - m); e[1] = __expf(a.y - m); e[2] = __expf(a.z - m); e[3] = __expf(a.w - m);
  e[4] = __expf(b.x - m); e[5] = __expf(b.y - m); e[6] = __expf(b.z - m); e[7] = __expf(b.w - m);
  float sum = e[0] + e[1] + e[2] + e[3] + e[4] + e[5] + e[6] + e[7];
#pragma unroll
  for (int o = 32; o > 0; o >>= 1) sum += __shfl_xor(sum, o);
  if ((tid & 63) == 0) reds[tid >> 6] = sum;
  __syncthreads();
  sum = reds[0] + reds[1] + reds[2] + reds[3];
  const float inv = 1.f / sum;
  u16x4 o1 = { f2bf(e[0] * inv), f2bf(e[1] * inv), f2bf(e[2] * inv), f2bf(e[3] * inv) };
  u16x4 o2 = { f2bf(e[4] * inv), f2bf(e[5] * inv), f2bf(e[6] * inv), f2bf(e[7] * inv) };
  u16x4* d = (u16x4*)(dst + row * 2048);
  d[tid * 2]     = o1;
  d[tid * 2 + 1] = o2;
}

__global__ void transpose_f32_to_bf16(const float* __restrict__ src, u16* __restrict__ dst,
                                      int R, int C) {
  __shared__ float t[32][33];
  const int c0 = blockIdx.x * 32, r0 = blockIdx.y * 32;
  const int tx = threadIdx.x, ty = threadIdx.y;
#pragma unroll
  for (int i = 0; i < 4; ++i)
    t[ty + i * 8][tx] = src[(long)(r0 + ty + i * 8) * C + c0 + tx];
  __syncthreads();
#pragma unroll
  for (int i = 0; i < 4; ++i)
    dst[(long)(c0 + ty + i * 8) * R + r0 + tx] = f2bf(t[tx][ty + i * 8]);
}

__global__ __launch_bounds__(256)
void convert_f32_to_bf16(const float* __restrict__ src, u16* __restrict__ dst, long n4) {
  long i = (long)blockIdx.x * 256 + threadIdx.x;
  if (i < n4) {
    float4 v = ((const float4*)src)[i];
    *(u16x4*)(dst + i * 4) = (u16x4){ f2bf(v.x), f2bf(v.y), f2bf(v.z), f2bf(v.w) };
  }
}

// camT = tanh(ctx * gate) * sigmoid(w0 + 0.5*w1)
__global__ __launch_bounds__(256)
void cam_tanh_kernel(const float* __restrict__ ctx, const float* __restrict__ gate,
                     const float* __restrict__ w0, const float* __restrict__ w1,
                     u16* __restrict__ out, int n) {
  int i = blockIdx.x * 256 + threadIdx.x;
  if (i < n) {
    const float lw = 1.f / (1.f + __expf(-(w0[0] + 0.5f * w1[0])));
    int d = i & 127;
    out[i] = f2bf(tanhf(ctx[i] * gate[d]) * lw);
  }
}

__global__ __launch_bounds__(256)
void zero_f32(float* __restrict__ p, int n) {
  int i = blockIdx.x * 256 + threadIdx.x;
  if (i < n) p[i] = 0.f;
}

extern "C" void kernel_launch(void* const* d_in, const int* in_sizes, int n_in,
                              void* d_out, int out_size, void* d_ws, size_t ws_size,
                              hipStream_t stream) {
  const float* hs       = (const float*)d_in[0];
  const float* c_attn_w = (const float*)d_in[1];
  const float* c_attn_b = (const float*)d_in[2];
  const float* c_proj_w = (const float*)d_in[3];
  const float* c_proj_b = (const float*)d_in[4];
  const float* cam_gate = (const float*)d_in[5];
  const float* cam_w0   = (const float*)d_in[6];
  const float* cam_w1   = (const float*)d_in[7];
  float* out = (float*)d_out;

  char* w = (char*)d_ws;
  u16*   hs_b    = (u16*)(w + 256);                  // 16 MB (reused as baseA)
  u16*   waT_b   = (u16*)(w + 256 + 16777216UL);     // 24 MB
  u16*   wpT_b   = (u16*)(w + 256 + 41943040UL);     // 8 MB
  u16*   qkv_b   = (u16*)(w + 256 + 50331648UL);     // 48 MB
  u16*   vT_b    = (u16*)(w + 256 + 100663296UL);    // 16 MB
  float* scoresF = (float*)(w + 256 + 117440512UL);  // 32 MB (reused as ctxE bf16)
  float* camS    = (float*)(w + 256 + 150994944UL);  // 32 MB (reused as P bf16)
  float* ctxF    = (float*)(w + 256 + 184549376UL);  // 2 MB
  u16*   camT_b  = (u16*)(w + 256 + 186646528UL);    // 1 MB
  u16* baseA_b = hs_b;
  u16* P_b     = (u16*)camS;
  u16* ctxE_b  = (u16*)scoresF;

  dim3 b256(256);
  const int LDSB = 147456;   // 3 bufs x 48 KiB

  hipFuncSetAttribute((const void*)g128q<true, true, false>,
                      hipFuncAttributeMaxDynamicSharedMemorySize, LDSB);
  hipFuncSetAttribute((const void*)g128q<false, false, false>,
                      hipFuncAttributeMaxDynamicSharedMemorySize, LDSB);
  hipFuncSetAttribute((const void*)g128q<false, false, true>,
                      hipFuncAttributeMaxDynamicSharedMemorySize, LDSB);
  hipFuncSetAttribute((const void*)g128q<true, false, false>,
                      hipFuncAttributeMaxDynamicSharedMemorySize, LDSB);
  hipFuncSetAttribute((const void*)g128q<false, true, false>,
                      hipFuncAttributeMaxDynamicSharedMemorySize, LDSB);

  convert_f32_to_bf16<<<dim3(8192), b256, 0, stream>>>(hs, hs_b, 2097152L);
  transpose_f32_to_bf16<<<dim3(192, 64), dim3(32, 8), 0, stream>>>(c_attn_w, waT_b, 2048, 6144);
  transpose_f32_to_bf16<<<dim3(64, 64), dim3(32, 8), 0, stream>>>(c_proj_w, wpT_b, 2048, 2048);

  // GEMM1: qkv = hs @ W_attn + b ; V-columns written transposed to vT_b.
  g128q<true, true, false><<<dim3(768, 1, 1), dim3(512), LDSB, stream>>>(
      hs_b, 2048, 0L, waT_b, 2048, 0L, 2048,
      nullptr, 0, 0L, nullptr, 0, 0L, 0,
      qkv_b, 6144, 0L, 1.f, c_attn_b, 48, 1, vT_b);

  // GEMM3: camS = Q_cam @ K_cam^T * SCALE (K=128 -> NT=2), 256 blocks
  g128q<false, false, false><<<dim3(128, 1, 2), dim3(512), LDSB, stream>>>(
      qkv_b, 6144, 2048L * 6144, qkv_b + 2048, 6144, 2048L * 6144, 128,
      nullptr, 0, 0L, nullptr, 0, 0L, 0,
      camS, 2048, 2048L * 2048, SCALE_QK, nullptr, 16, 0, nullptr);

  // base_A = softmax(camS) -> bf16
  softmax_rows2048<<<dim3(4096), b256, 0, stream>>>(camS, baseA_b);

  // GEMM4: cam_ctx = base_A @ V_cam — split-K x8
  zero_f32<<<dim3(2048), b256, 0, stream>>>(ctxF, 524288);
  gemm_bt_splitk<<<dim3(1, 16, 16), b256, 0, stream>>>(
      baseA_b, 2048, 2048L * 2048, vT_b, 2048, 2048L * 2048,
      ctxF, 128, 2048L * 128, 256, 1.f);

  // camT = tanh(cam_ctx * gate) * lw -> bf16
  cam_tanh_kernel<<<dim3(2048), b256, 0, stream>>>(ctxF, cam_gate, cam_w0, cam_w1,
                                                   camT_b, 524288);

  // GEMM2' (fused GEMM5): scores = SCALE*( Q@K^T + camT@K_cam^T ), f32
  g128q<false, false, true><<<dim3(128, 1, 2), dim3(512), LDSB, stream>>>(
      qkv_b, 6144, 2048L * 6144, qkv_b + 2048, 6144, 2048L * 6144, 2048,
      camT_b, 128, 2048L * 128, qkv_b + 2048, 6144, 2048L * 6144, 128,
      scoresF, 2048, 2048L * 2048, SCALE_QK, nullptr, 16, 0, nullptr);

  // P = softmax(scores) -> bf16
  softmax_rows2048<<<dim3(4096), b256, 0, stream>>>(scoresF, P_b);

  // GEMM6: context (bf16) = P @ V
  g128q<true, false, false><<<dim3(128, 1, 2), dim3(512), LDSB, stream>>>(
      P_b, 2048, 2048L * 2048, vT_b, 2048, 2048L * 2048, 2048,
      nullptr, 0, 0L, nullptr, 0, 0L, 0,
      ctxE_b, 2048, 2048L * 2048, 1.f, nullptr, 16, 0, nullptr);

  // GEMM7: out (f32) = context @ W_proj + b  (batches stacked: M=4096)
  g128q<false, true, false><<<dim3(256, 1, 1), dim3(512), LDSB, stream>>>(
      ctxE_b, 2048, 0L, wpT_b, 2048, 0L, 2048,
      nullptr, 0, 0L, nullptr, 0, 0L, 0,
      out, 2048, 0L, 1.f, c_proj_b, 16, 0, nullptr);
}